// Round 4
// baseline (1992.439 us; speedup 1.0000x reference)
//
#include <hip/hip_runtime.h>
#include <math.h>

// Problem constants
#define BATCH  16384
#define HID    4096
#define NCOLS  1536     // NUM_SUB * H * 2
#define NGRP   384      // NUM_SUB * H / RANK

// Gap threshold: bf16x3-path score error vs fp64 is ~2.5e-6 worst case
// (RTZ-hi residual 2^-8 rms -> ~2e-6 logit std; score sens. 0.025; plus fp32
// transcendentals ~1e-6). 2e-5 = 8x margin; validated at this margin ratio.
#define GAP_MIN 2.0e-5f

typedef unsigned short u16;
typedef short bf16x8 __attribute__((ext_vector_type(8)));
typedef float f32x4  __attribute__((ext_vector_type(4)));

__device__ __forceinline__ int budget_of(float lat) {
    float un = rintf(lat * 512.0f);           // round-half-even like jnp.round
    un = fminf(fmaxf(un, 128.0f), 512.0f);
    return (int)un - 128;                     // 0..384
}

__device__ __forceinline__ double gumbel_d(float uu) {
    double v = (double)uu * (1.0 - 2.0e-6) + 1.0e-6;
    return -log(-log(v));
}

// fp32 gumbel, accurate at BOTH tails.
__device__ __forceinline__ float gumbel_f(float u) {
    float inner;
    if (u <= 0.5f) {
        float v = fmaf(u, 0.999998f, 1e-6f);          // u*(1-2e-6)+1e-6
        inner = -logf(v);
    } else {
        float t1 = 1.0f - u;                          // exact
        float w  = fmaf(1e-6f, fmaf(2.0f, u, -1.0f), t1);
        inner = -log1pf(-w);
    }
    return -logf(inner);
}

__device__ __forceinline__ float score_f(float l0, float l1, float l2, float l3,
                                         float4 uv) {
    const float d0 = ((l0 + gumbel_f(uv.x)) - (l1 + gumbel_f(uv.y))) * 0.2f;
    const float d1 = ((l2 + gumbel_f(uv.z)) - (l3 + gumbel_f(uv.w))) * 0.2f;
    const float p0 = 1.0f / (1.0f + expf(-d0));
    const float p1 = 1.0f / (1.0f + expf(-d1));
    return 0.5f * (p0 + p1);
}

// ---- bf16 split helpers ----
__device__ __forceinline__ unsigned bf16_rne_bits(float f) {
    unsigned b = __float_as_uint(f);
    return (b + 0x7FFFu + ((b >> 16) & 1u)) >> 16;
}

// Hot-path split: hi = RTZ-bf16 (bitmask), lo = RNE-bf16(x - hi).
__device__ __forceinline__ void split4(const float4 v, uint2& hi, uint2& lo) {
    const unsigned bx = __float_as_uint(v.x), by = __float_as_uint(v.y),
                   bz = __float_as_uint(v.z), bw = __float_as_uint(v.w);
    const unsigned hx = bx & 0xFFFF0000u, hy = by & 0xFFFF0000u,
                   hz = bz & 0xFFFF0000u, hw = bw & 0xFFFF0000u;
    hi.x = (hx >> 16) | hy;
    hi.y = (hz >> 16) | hw;
    const float lx = v.x - __uint_as_float(hx);
    const float ly = v.y - __uint_as_float(hy);
    const float lz = v.z - __uint_as_float(hz);
    const float lw = v.w - __uint_as_float(hw);
    lo.x = bf16_rne_bits(lx) | (bf16_rne_bits(ly) << 16);
    lo.y = bf16_rne_bits(lz) | (bf16_rne_bits(lw) << 16);
}

// Async global->LDS, 16B per lane. LDS dest is wave-uniform base + lane*16.
__device__ __forceinline__ void gload16(const u16* g, u16* l) {
    __builtin_amdgcn_global_load_lds(
        (const __attribute__((address_space(1))) unsigned int*)g,
        (__attribute__((address_space(3))) unsigned int*)l, 16, 0, 0);
}

// Per-sample classification + trivial-output fill + compaction of interior rows.
__global__ __launch_bounds__(64)
void prefilter_kernel(const float* __restrict__ latency, float* __restrict__ out,
                      int* __restrict__ count, int* __restrict__ idx)
{
    const int b = blockIdx.x;
    const int t = threadIdx.x;
    const int budget = budget_of(latency[b]);
    float* obase = out + (size_t)b * 2048;

    const float4 ones = make_float4(1.f, 1.f, 1.f, 1.f);
    ((float4*)obase)[t]      = ones;   // prefix: layers 0..7 all ones
    ((float4*)obase)[t + 64] = ones;

    if (budget > 0 && budget < NGRP) {
        if (t == 0) { int s = atomicAdd(count, 1); idx[s] = b; }
    } else {
        const float K = (budget == 0) ? 0.0f : 1.0f;
#pragma unroll
        for (int j = 0; j < 6; ++j) {
            const int i = j * 64 + t;
            const int p = i * 4;             // p = l*64 + s*32 + h
            const int s = (p >> 5) & 1;
            const float v = s ? (1.0f - K) : K;
            ((float4*)(obase + 512))[i] = make_float4(v, v, v, v);
        }
    }
}

// One-time W transpose + bf16 hi/lo split into a kb-major TILED layout:
//   wt[colblk 12][ktile 128][kb 4][n 128][e 8]  (u16)
// so GEMM B-staging is a LINEAR, fully-coalesced global_load_lds and the
// LDS image [kb][n][8] gives conflict-free ds_read_b128 fragments.
__global__ __launch_bounds__(256)
void convert_w(const float* __restrict__ W, u16* __restrict__ wt_hi,
               u16* __restrict__ wt_lo)
{
    __shared__ float sT[32][33];
    const int n0 = blockIdx.x * 32, k0 = blockIdx.y * 32;
    const int t  = threadIdx.x;
    {
        const int lr = t >> 3, lc = (t & 7) * 4;
        const float4 v = *(const float4*)(W + (size_t)(k0 + lr) * NCOLS + n0 + lc);
        sT[lr][lc] = v.x; sT[lr][lc + 1] = v.y; sT[lr][lc + 2] = v.z; sT[lr][lc + 3] = v.w;
    }
    __syncthreads();
    const int ln = t >> 3, lk = (t & 7) * 4;     // ln: n-local, lk: k-local
    unsigned hb[4], lb[4];
#pragma unroll
    for (int j = 0; j < 4; ++j) {
        const float xv = sT[lk + j][ln];
        const unsigned h = bf16_rne_bits(xv);          // RNE hi for W (one-time)
        const float hf = __uint_as_float(h << 16);
        hb[j] = h;
        lb[j] = bf16_rne_bits(xv - hf);
    }
    uint2 hw, lw;
    hw.x = hb[0] | (hb[1] << 16); hw.y = hb[2] | (hb[3] << 16);
    lw.x = lb[0] | (lb[1] << 16); lw.y = lb[2] | (lb[3] << 16);
    const int gn = n0 + ln;
    const size_t off = ((size_t)((gn >> 7) * 128 + (k0 >> 5)) * 4 + (lk >> 3)) * 1024
                     + (size_t)(gn & 127) * 8 + (lk & 7);
    *(uint2*)(wt_hi + off) = hw;
    *(uint2*)(wt_lo + off) = lw;
}

// bf16x3 MFMA GEMM (128x128 tile, BK=32) + fp32 gumbel-softmax scores.
// DOUBLE-BUFFERED (T3-min): per K-step, issue x-prefetch + gload B(t+1) into
// buf^1 BEFORE computing tile t; split+ds_write A(t+1) AFTER the MFMAs; one
// barrier per K-step. Staging overlaps MFMA/LDS-read (r3 post-mortem: serial
// 2-barrier structure ran at the sum of pipe demands, 2576 cyc/block-K-step).
// NOTE: every access to acc[][] must be compile-time-indexed (full unroll) —
// a single runtime index demotes the whole array to scratch (r1 post-mortem).
#define GSTEP(SAC, SBC, SAN, SBN, KCUR, HAVE_NEXT)                             \
    {                                                                          \
        float4 a00, a01, a10, a11;                                             \
        if (HAVE_NEXT) {                                                       \
            a00 = *(const float4*)(x + xoff0 + (KCUR) + 32);                   \
            a01 = *(const float4*)(x + xoff0 + (KCUR) + 36);                   \
            a10 = *(const float4*)(x + xoff1 + (KCUR) + 32);                   \
            a11 = *(const float4*)(x + xoff1 + (KCUR) + 36);                   \
            const size_t bs = bsrc0 + (size_t)(((KCUR) >> 5) + 1) * 4096;      \
            gload16(wt_hi + bs,        SBN + ldsB0);                           \
            gload16(wt_hi + bs + 2048, SBN + ldsB1);                           \
            gload16(wt_lo + bs,        SBN + 4096 + ldsB0);                    \
            gload16(wt_lo + bs + 2048, SBN + 4096 + ldsB1);                    \
        }                                                                      \
        bf16x8 bh[4], bl[4];                                                   \
        _Pragma("unroll")                                                      \
        for (int ni = 0; ni < 4; ++ni) {                                       \
            bh[ni] = *(const bf16x8*)&SBC[boff + ni * 128];                    \
            bl[ni] = *(const bf16x8*)&SBC[4096 + boff + ni * 128];             \
        }                                                                      \
        _Pragma("unroll")                                                      \
        for (int mi = 0; mi < 4; ++mi) {                                       \
            const bf16x8 ah = *(const bf16x8*)&SAC[aoff + mi * 640];           \
            const bf16x8 al = *(const bf16x8*)&SAC[5120 + aoff + mi * 640];    \
            _Pragma("unroll")                                                  \
            for (int ni = 0; ni < 4; ++ni) {                                   \
                acc[mi][ni] = __builtin_amdgcn_mfma_f32_16x16x32_bf16(ah, bh[ni], acc[mi][ni], 0, 0, 0); \
                acc[mi][ni] = __builtin_amdgcn_mfma_f32_16x16x32_bf16(ah, bl[ni], acc[mi][ni], 0, 0, 0); \
                acc[mi][ni] = __builtin_amdgcn_mfma_f32_16x16x32_bf16(al, bh[ni], acc[mi][ni], 0, 0, 0); \
            }                                                                  \
        }                                                                      \
        if (HAVE_NEXT) {                                                       \
            uint2 h0, l0, h1, l1;                                              \
            split4(a00, h0, l0); split4(a01, h1, l1);                          \
            *(uint4*)&SAN[arow]        = make_uint4(h0.x, h0.y, h1.x, h1.y);   \
            *(uint4*)&SAN[5120 + arow] = make_uint4(l0.x, l0.y, l1.x, l1.y);   \
            split4(a10, h0, l0); split4(a11, h1, l1);                          \
            *(uint4*)&SAN[arow2]        = make_uint4(h0.x, h0.y, h1.x, h1.y);  \
            *(uint4*)&SAN[5120 + arow2] = make_uint4(l0.x, l0.y, l1.x, l1.y);  \
        }                                                                      \
        __syncthreads();                                                       \
    }

__global__ __launch_bounds__(256)
void gemm_bf16x3(const float* __restrict__ x, const u16* __restrict__ wt_hi,
                 const u16* __restrict__ wt_lo, const float* __restrict__ bias,
                 const float* __restrict__ uu, const int* __restrict__ idx,
                 const int* __restrict__ count, float* __restrict__ scoresf)
{
    // A: [buf 2][plane 2][128 rows][40 u16]  (pad->80B rows, 2-way banks free)
    // B: [buf 2][plane 2][4 kb][128 n][8 e]  (linear gload_lds dest)
    __shared__ __align__(16) u16 sMem[2 * 10240 + 2 * 8192];   // 73728 B
    __shared__ int rid[128];
    u16* const sA0 = sMem;            // buf0 A (lo-plane at +5120)
    u16* const sA1 = sMem + 10240;    // buf1 A
    u16* const sB0 = sMem + 20480;    // buf0 B (lo-plane at +4096)
    u16* const sB1 = sMem + 28672;    // buf1 B

    const int cnt  = *count;
    const int row0 = blockIdx.y * 128;
    if (row0 >= cnt) return;
    const int cb   = blockIdx.x;
    const int col0 = cb * 128;
    const int t    = threadIdx.x;

    if (t < 128) rid[t] = idx[min(row0 + t, cnt - 1)];
    __syncthreads();

    // ---- A staging maps ----
    const int ar  = t >> 2;             // A rows ar and ar+64
    const int akc = (t & 3) << 3;       // k offset {0,8,16,24}
    const int arow  = ar * 40 + akc;
    const int arow2 = (ar + 64) * 40 + akc;
    const size_t xoff0 = (size_t)rid[ar] * HID + akc;
    const size_t xoff1 = (size_t)rid[ar + 64] * HID + akc;

    // ---- B staging (global_load_lds) ----
    const int wave = t >> 6;
    const size_t bsrc0 = (size_t)cb * 524288 + (size_t)t * 8;  // + kt*4096
    const int ldsB0 = wave * 512;          // issue 0 wave base (u16 units)
    const int ldsB1 = 2048 + wave * 512;   // issue 1

    // ---- fragment maps ----
    const int lane = t & 63;
    const int wr = wave >> 1;           // wave row half
    const int wc = wave & 1;            // wave col half
    const int fr = lane & 15;
    const int kb = lane >> 4;           // 0..3
    const int aoff = (wr * 64 + fr) * 40 + kb * 8;    // + plane*5120 + mi*640
    const int boff = kb * 1024 + (wc * 64 + fr) * 8;  // + plane*4096 + ni*128

    f32x4 acc[4][4] = {};

    // ---- prologue: stage tile 0 into buf0 ----
    {
        float4 a00 = *(const float4*)(x + xoff0);
        float4 a01 = *(const float4*)(x + xoff0 + 4);
        float4 a10 = *(const float4*)(x + xoff1);
        float4 a11 = *(const float4*)(x + xoff1 + 4);
        gload16(wt_hi + bsrc0,        sB0 + ldsB0);
        gload16(wt_hi + bsrc0 + 2048, sB0 + ldsB1);
        gload16(wt_lo + bsrc0,        sB0 + 4096 + ldsB0);
        gload16(wt_lo + bsrc0 + 2048, sB0 + 4096 + ldsB1);
        uint2 h0, l0, h1, l1;
        split4(a00, h0, l0); split4(a01, h1, l1);
        *(uint4*)&sA0[arow]        = make_uint4(h0.x, h0.y, h1.x, h1.y);
        *(uint4*)&sA0[5120 + arow] = make_uint4(l0.x, l0.y, l1.x, l1.y);
        split4(a10, h0, l0); split4(a11, h1, l1);
        *(uint4*)&sA0[arow2]        = make_uint4(h0.x, h0.y, h1.x, h1.y);
        *(uint4*)&sA0[5120 + arow2] = make_uint4(l0.x, l0.y, l1.x, l1.y);
    }
    __syncthreads();

#pragma unroll 1
    for (int k0 = 0; k0 < HID; k0 += 64) {
        GSTEP(sA0, sB0, sA1, sB1, k0, true);             // even tile: next odd
        GSTEP(sA1, sB1, sA0, sB0, k0 + 32, (k0 + 64 < HID));
    }

    // ---- epilogue: LDS transpose of MFMA layout, then scores ----
    // MFMA D layout: col = lane&15, row = 4*(lane>>4)+r  (per frag)
    // FULL unroll (compile-time mi) — see scratch-demotion note above.
    float* const sOut = (float*)sMem;                  // 4 waves x [16][68] f32
    float* const sW   = sOut + wave * (16 * 68);
    const int gb = (col0 >> 2) + wc * 16;              // global group base (wave)

#pragma unroll
    for (int mi = 0; mi < 4; ++mi) {
        __syncthreads();
#pragma unroll
        for (int ni = 0; ni < 4; ++ni)
#pragma unroll
            for (int r = 0; r < 4; ++r)
                sW[(kb * 4 + r) * 68 + ni * 16 + fr] = acc[mi][ni][r];
        __syncthreads();

        const int lr    = fr;                          // row 0..15
        const int gq    = kb;                          // group quad 0..3
        const int row_l = wr * 64 + mi * 16 + lr;      // local compact row
        const int cr    = row0 + row_l;
        const int orig  = rid[row_l];
        const float* so = sW + lr * 68 + gq * 16;
        const int g0    = gb + gq * 4;

        float s[4];
#pragma unroll
        for (int j = 0; j < 4; ++j) {
            const int g = g0 + j;
            const float4 lv = *(const float4*)(so + 4 * j);
            const float4 bv = *(const float4*)(bias + 4 * g);
            const float4 uv = *(const float4*)(uu + (size_t)orig * NCOLS + 4 * g);
            s[j] = score_f(lv.x + bv.x, lv.y + bv.y, lv.z + bv.z, lv.w + bv.w, uv);
        }
        *(float4*)&scoresf[(size_t)cr * NGRP + g0] = make_float4(s[0], s[1], s[2], s[3]);
    }
}

// fp32 selection with boundary-gap certification; flags close calls for fp64.
// Rank loop uses b128 LDS reads (broadcast) — 4x fewer ds ops than b32.
__global__ __launch_bounds__(384)
void select_fast(const float* __restrict__ scoresf, const float* __restrict__ latency,
                 const int* __restrict__ idx, const int* __restrict__ count,
                 float* __restrict__ out, int* __restrict__ ridx, int* __restrict__ rcount)
{
    const int b = blockIdx.x;
    if (b >= *count) return;
    const int t = threadIdx.x;
    const int orig = idx[b];

    __shared__ __align__(16) float sm[NGRP];
    __shared__ float bnd[2];
    __shared__ int   flag;
    const float sg = scoresf[(size_t)b * NGRP + t];
    sm[t] = sg;
    if (t == 0) flag = 0;
    const int budget = budget_of(latency[orig]);   // 1..383 here
    __syncthreads();

    int rank = 0;
#pragma unroll 4
    for (int j = 0; j < NGRP; j += 4) {
        const float4 v = *(const float4*)&sm[j];
        rank += (v.x > sg || (v.x == sg && (j + 0) < t)) ? 1 : 0;
        rank += (v.y > sg || (v.y == sg && (j + 1) < t)) ? 1 : 0;
        rank += (v.z > sg || (v.z == sg && (j + 2) < t)) ? 1 : 0;
        rank += (v.w > sg || (v.w == sg && (j + 3) < t)) ? 1 : 0;
    }
    if (rank == budget - 1) bnd[0] = sg;   // min of kept set
    if (rank == budget)     bnd[1] = sg;   // max of dropped set
    __syncthreads();
    if (t == 0 && (bnd[0] - bnd[1] < GAP_MIN)) {
        flag = 1;
        ridx[atomicAdd(rcount, 1)] = orig;
    }
    __syncthreads();
    if (flag) return;

    const float keep = (rank < budget) ? 1.0f : 0.0f;
    float* p = out + (size_t)orig * 2048 + 512 + (size_t)(t >> 4) * 64;
    const int h2 = (t & 15) << 1;
    *(float2*)(p + h2)      = make_float2(keep, keep);
    *(float2*)(p + 32 + h2) = make_float2(1.0f - keep, 1.0f - keep);
}

// fp64 repair GEMM over flagged rows only. BM=32 for block-level parallelism.
__global__ __launch_bounds__(256)
void gemm64_repair(const float* __restrict__ x, const float* __restrict__ W,
                   const float* __restrict__ bias, const float* __restrict__ u,
                   const int* __restrict__ ridx, const int* __restrict__ rcount,
                   double* __restrict__ scores)
{
    __shared__ float As[16][36];
    __shared__ float Bs[16][68];
    __shared__ int   rid[32];

    const int cnt  = *rcount;
    const int row0 = blockIdx.y * 32;
    if (row0 >= cnt) return;
    const int col0 = blockIdx.x * 64;
    const int t    = threadIdx.x;

    if (t < 32) rid[t] = ridx[min(row0 + t, cnt - 1)];
    __syncthreads();

    const bool doA = (t < 128);
    const int ar  = t >> 2;            // 0..31 when doA
    const int akc = (t & 3) << 2;
    const int bkr = t >> 4;
    const int bnc = (t & 15) << 2;

    size_t xoff = 0;
    if (doA) xoff = (size_t)rid[ar] * HID + akc;
    const float* wp = W + (size_t)bkr * NCOLS + col0 + bnc;

    const int ty = t >> 4;             // rows 2ty, 2ty+1
    const int tx = t & 15;

    double acc[2][4] = {};

    float4 a0 = make_float4(0, 0, 0, 0);
    if (doA) a0 = *(const float4*)(x + xoff);
    float4 b0 = *(const float4*)(wp);

    for (int k0 = 0; k0 < HID; k0 += 16) {
        __syncthreads();
        if (doA) {
            As[akc + 0][ar] = a0.x; As[akc + 1][ar] = a0.y;
            As[akc + 2][ar] = a0.z; As[akc + 3][ar] = a0.w;
        }
        *(float4*)&Bs[bkr][bnc] = b0;
        __syncthreads();
        if (k0 + 16 < HID) {
            if (doA) a0 = *(const float4*)(x + xoff + k0 + 16);
            b0 = *(const float4*)(wp + (size_t)(k0 + 16) * NCOLS);
        }
#pragma unroll
        for (int k = 0; k < 16; ++k) {
            const double a0d = (double)As[k][ty * 2];
            const double a1d = (double)As[k][ty * 2 + 1];
            const float4 bf  = *(const float4*)&Bs[k][tx * 4];
            const double bd[4] = {(double)bf.x, (double)bf.y, (double)bf.z, (double)bf.w};
#pragma unroll
            for (int j = 0; j < 4; ++j) {
                acc[0][j] = fma(a0d, bd[j], acc[0][j]);
                acc[1][j] = fma(a1d, bd[j], acc[1][j]);
            }
        }
    }

    const int g = (col0 >> 2) + tx;
    const double bs0 = (double)bias[4 * g + 0];
    const double bs1 = (double)bias[4 * g + 1];
    const double bs2 = (double)bias[4 * g + 2];
    const double bs3 = (double)bias[4 * g + 3];
#pragma unroll
    for (int i = 0; i < 2; ++i) {
        const int rl   = ty * 2 + i;
        const int cr   = row0 + rl;
        const int orig = rid[rl];
        const float4 uv = *(const float4*)(u + (size_t)orig * NCOLS + 4 * g);
        const double l0 = acc[i][0] + bs0;
        const double l1 = acc[i][1] + bs1;
        const double l2 = acc[i][2] + bs2;
        const double l3 = acc[i][3] + bs3;
        const double d0 = ((l0 + gumbel_d(uv.x)) - (l1 + gumbel_d(uv.y))) / 5.0;
        const double d1 = ((l2 + gumbel_d(uv.z)) - (l3 + gumbel_d(uv.w))) / 5.0;
        const double p0 = 1.0 / (1.0 + exp(-d0));
        const double p1 = 1.0 / (1.0 + exp(-d1));
        scores[(size_t)cr * NGRP + g] = 0.5 * (p0 + p1);
    }
}

// fp64 selection for flagged rows (no gap test).
__global__ __launch_bounds__(384)
void select_repair(const double* __restrict__ scores, const float* __restrict__ latency,
                   const int* __restrict__ ridx, const int* __restrict__ rcount,
                   float* __restrict__ out)
{
    const int b = blockIdx.x;
    if (b >= *rcount) return;
    const int t = threadIdx.x;
    const int orig = ridx[b];

    __shared__ __align__(16) double sm[NGRP];
    const double sg = scores[(size_t)b * NGRP + t];
    sm[t] = sg;
    const int budget = budget_of(latency[orig]);
    __syncthreads();

    int rank = 0;
#pragma unroll 4
    for (int j = 0; j < NGRP; j += 2) {
        const double2 v = *(const double2*)&sm[j];
        rank += (v.x > sg || (v.x == sg && (j + 0) < t)) ? 1 : 0;
        rank += (v.y > sg || (v.y == sg && (j + 1) < t)) ? 1 : 0;
    }
    const float keep = (rank < budget) ? 1.0f : 0.0f;

    float* p = out + (size_t)orig * 2048 + 512 + (size_t)(t >> 4) * 64;
    const int h2 = (t & 15) << 1;
    *(float2*)(p + h2)      = make_float2(keep, keep);
    *(float2*)(p + 32 + h2) = make_float2(1.0f - keep, 1.0f - keep);
}

extern "C" void kernel_launch(void* const* d_in, const int* in_sizes, int n_in,
                              void* d_out, int out_size, void* d_ws, size_t ws_size,
                              hipStream_t stream) {
    const float* x       = (const float*)d_in[0];
    const float* latency = (const float*)d_in[1];
    const float* W       = (const float*)d_in[2];
    const float* bias    = (const float*)d_in[3];
    const float* u       = (const float*)d_in[4];
    float* out           = (float*)d_out;

    // ws layout (total 50,462,976 B):
    //   [count,rcount.. 256B][idx 64KB][ridx 64KB]
    //   [WT_hi 12.58MB][WT_lo 12.58MB][scoresf 25.17MB]
    //   scores64 (fp64, 50.33MB) ALIASES [WT_hi..scoresf]: WT planes are dead
    //   after gemm_bf16x3, scoresf is dead after select_fast, and gemm64_repair
    //   (which writes scores64) runs after select_fast. Lifetimes disjoint.
    int*    count   = (int*)d_ws;
    int*    rcount  = (int*)((char*)d_ws + 4);
    int*    idx     = (int*)((char*)d_ws + 256);
    int*    ridx    = (int*)((char*)d_ws + 256 + 65536);
    u16*    wt_hi   = (u16*)((char*)d_ws + 131328);
    u16*    wt_lo   = (u16*)((char*)d_ws + 131328 + 12582912);
    float*  scoresf = (float*)((char*)d_ws + 131328 + 25165824);
    double* scores64= (double*)((char*)d_ws + 131328);

    hipMemsetAsync(d_ws, 0, 256, stream);
    convert_w<<<dim3(NCOLS / 32, HID / 32), 256, 0, stream>>>(W, wt_hi, wt_lo);
    prefilter_kernel<<<BATCH, 64, 0, stream>>>(latency, out, count, idx);
    gemm_bf16x3<<<dim3(NCOLS / 128, BATCH / 128), 256, 0, stream>>>(
        x, wt_hi, wt_lo, bias, u, idx, count, scoresf);
    select_fast<<<BATCH, NGRP, 0, stream>>>(scoresf, latency, idx, count, out, ridx, rcount);
    gemm64_repair<<<dim3(NCOLS / 64, BATCH / 32), 256, 0, stream>>>(
        x, W, bias, u, ridx, rcount, scores64);
    select_repair<<<BATCH, NGRP, 0, stream>>>(scores64, latency, ridx, rcount, out);
}

// Round 5
// 1388.942 us; speedup vs baseline: 1.4345x; 1.4345x over previous
//
#include <hip/hip_runtime.h>
#include <math.h>

// Problem constants
#define BATCH  16384
#define HID    4096
#define NCOLS  1536     // NUM_SUB * H * 2
#define NGRP   384      // NUM_SUB * H / RANK

// Gap threshold: bf16x3-path score error vs fp64 is ~2.5e-6 worst case.
#define GAP_MIN 2.0e-5f
// Certainty margin for window classification (>= 2x worst-case fp32 error).
#define MARG    1.0e-5f
#define WMAX    16

typedef unsigned short u16;
typedef short bf16x8 __attribute__((ext_vector_type(8)));
typedef float f32x4  __attribute__((ext_vector_type(4)));

__device__ __forceinline__ int budget_of(float lat) {
    float un = rintf(lat * 512.0f);           // round-half-even like jnp.round
    un = fminf(fmaxf(un, 128.0f), 512.0f);
    return (int)un - 128;                     // 0..384
}

__device__ __forceinline__ double gumbel_d(float uu) {
    double v = (double)uu * (1.0 - 2.0e-6) + 1.0e-6;
    return -log(-log(v));
}

// fp32 gumbel, accurate at BOTH tails.
__device__ __forceinline__ float gumbel_f(float u) {
    float inner;
    if (u <= 0.5f) {
        float v = fmaf(u, 0.999998f, 1e-6f);          // u*(1-2e-6)+1e-6
        inner = -logf(v);
    } else {
        float t1 = 1.0f - u;                          // exact
        float w  = fmaf(1e-6f, fmaf(2.0f, u, -1.0f), t1);
        inner = -log1pf(-w);
    }
    return -logf(inner);
}

__device__ __forceinline__ float score_f(float l0, float l1, float l2, float l3,
                                         float4 uv) {
    const float d0 = ((l0 + gumbel_f(uv.x)) - (l1 + gumbel_f(uv.y))) * 0.2f;
    const float d1 = ((l2 + gumbel_f(uv.z)) - (l3 + gumbel_f(uv.w))) * 0.2f;
    const float p0 = 1.0f / (1.0f + expf(-d0));
    const float p1 = 1.0f / (1.0f + expf(-d1));
    return 0.5f * (p0 + p1);
}

// ---- bf16 split helpers ----
__device__ __forceinline__ unsigned bf16_rne_bits(float f) {
    unsigned b = __float_as_uint(f);
    return (b + 0x7FFFu + ((b >> 16) & 1u)) >> 16;
}

// Hot-path split: hi = RTZ-bf16 (bitmask), lo = RNE-bf16(x - hi).
__device__ __forceinline__ void split4(const float4 v, uint2& hi, uint2& lo) {
    const unsigned bx = __float_as_uint(v.x), by = __float_as_uint(v.y),
                   bz = __float_as_uint(v.z), bw = __float_as_uint(v.w);
    const unsigned hx = bx & 0xFFFF0000u, hy = by & 0xFFFF0000u,
                   hz = bz & 0xFFFF0000u, hw = bw & 0xFFFF0000u;
    hi.x = (hx >> 16) | hy;
    hi.y = (hz >> 16) | hw;
    const float lx = v.x - __uint_as_float(hx);
    const float ly = v.y - __uint_as_float(hy);
    const float lz = v.z - __uint_as_float(hz);
    const float lw = v.w - __uint_as_float(hw);
    lo.x = bf16_rne_bits(lx) | (bf16_rne_bits(ly) << 16);
    lo.y = bf16_rne_bits(lz) | (bf16_rne_bits(lw) << 16);
}

// Async global->LDS, 16B per lane. LDS dest is wave-uniform base + lane*16.
__device__ __forceinline__ void gload16(const u16* g, u16* l) {
    __builtin_amdgcn_global_load_lds(
        (const __attribute__((address_space(1))) unsigned int*)g,
        (__attribute__((address_space(3))) unsigned int*)l, 16, 0, 0);
}

// Per-sample classification + trivial-output fill + compaction of interior rows.
__global__ __launch_bounds__(64)
void prefilter_kernel(const float* __restrict__ latency, float* __restrict__ out,
                      int* __restrict__ count, int* __restrict__ idx)
{
    const int b = blockIdx.x;
    const int t = threadIdx.x;
    const int budget = budget_of(latency[b]);
    float* obase = out + (size_t)b * 2048;

    const float4 ones = make_float4(1.f, 1.f, 1.f, 1.f);
    ((float4*)obase)[t]      = ones;   // prefix: layers 0..7 all ones
    ((float4*)obase)[t + 64] = ones;

    if (budget > 0 && budget < NGRP) {
        if (t == 0) { int s = atomicAdd(count, 1); idx[s] = b; }
    } else {
        const float K = (budget == 0) ? 0.0f : 1.0f;
#pragma unroll
        for (int j = 0; j < 6; ++j) {
            const int i = j * 64 + t;
            const int p = i * 4;             // p = l*64 + s*32 + h
            const int s = (p >> 5) & 1;
            const float v = s ? (1.0f - K) : K;
            ((float4*)(obase + 512))[i] = make_float4(v, v, v, v);
        }
    }
}

// One-time W transpose + bf16 hi/lo split into a kb-major TILED layout:
//   wt[colblk 12][ktile 128][kb 4][n 128][e 8]  (u16)
__global__ __launch_bounds__(256)
void convert_w(const float* __restrict__ W, u16* __restrict__ wt_hi,
               u16* __restrict__ wt_lo)
{
    __shared__ float sT[32][33];
    const int n0 = blockIdx.x * 32, k0 = blockIdx.y * 32;
    const int t  = threadIdx.x;
    {
        const int lr = t >> 3, lc = (t & 7) * 4;
        const float4 v = *(const float4*)(W + (size_t)(k0 + lr) * NCOLS + n0 + lc);
        sT[lr][lc] = v.x; sT[lr][lc + 1] = v.y; sT[lr][lc + 2] = v.z; sT[lr][lc + 3] = v.w;
    }
    __syncthreads();
    const int ln = t >> 3, lk = (t & 7) * 4;     // ln: n-local, lk: k-local
    unsigned hb[4], lb[4];
#pragma unroll
    for (int j = 0; j < 4; ++j) {
        const float xv = sT[lk + j][ln];
        const unsigned h = bf16_rne_bits(xv);          // RNE hi for W (one-time)
        const float hf = __uint_as_float(h << 16);
        hb[j] = h;
        lb[j] = bf16_rne_bits(xv - hf);
    }
    uint2 hw, lw;
    hw.x = hb[0] | (hb[1] << 16); hw.y = hb[2] | (hb[3] << 16);
    lw.x = lb[0] | (lb[1] << 16); lw.y = lb[2] | (lb[3] << 16);
    const int gn = n0 + ln;
    const size_t off = ((size_t)((gn >> 7) * 128 + (k0 >> 5)) * 4 + (lk >> 3)) * 1024
                     + (size_t)(gn & 127) * 8 + (lk & 7);
    *(uint2*)(wt_hi + off) = hw;
    *(uint2*)(wt_lo + off) = lw;
}

// bf16x3 MFMA GEMM (128x128 tile, BK=32) + fp32 gumbel-softmax scores.
// r3-proven single-buffer 2-barrier structure (explicit dbuf REGRESSED in r4:
// LDS 74KB + VGPR 100 cut occupancy 26->19%, 618->1034 us — trap #5).
// Grid is (rb=128, cb=12): blocks sharing an x row-panel have bid == rb mod 8
// -> same XCD -> x panel fetched once per XCD, not 8x.
// NOTE: every access to acc[][] must be compile-time-indexed (full unroll).
__global__ __launch_bounds__(256)
void gemm_bf16x3(const float* __restrict__ x, const u16* __restrict__ wt_hi,
                 const u16* __restrict__ wt_lo, const float* __restrict__ bias,
                 const float* __restrict__ uu, const int* __restrict__ idx,
                 const int* __restrict__ count, float* __restrict__ scoresf)
{
    // A planes: [128][40] u16 (pad->80B rows, 2-way banks = free)
    // B planes: [4 kb][128 n][8 e] u16 linear (gload_lds dest; reads 2-way free)
    __shared__ __align__(16) u16 sMem[2 * 5120 + 2 * 4096];   // 36864 B
    __shared__ int rid[128];
    u16* const sAh = sMem;
    u16* const sAl = sMem + 5120;
    u16* const sBh = sMem + 10240;
    u16* const sBl = sMem + 14336;

    const int cnt  = *count;
    const int row0 = blockIdx.x * 128;
    if (row0 >= cnt) return;
    const int cb   = blockIdx.y;
    const int col0 = cb * 128;
    const int t    = threadIdx.x;

    if (t < 128) rid[t] = idx[min(row0 + t, cnt - 1)];
    __syncthreads();

    // ---- A staging maps ----
    const int ar  = t >> 2;             // A rows ar and ar+64
    const int akc = (t & 3) << 3;       // k offset {0,8,16,24}
    const int arow  = ar * 40 + akc;
    const int arow2 = (ar + 64) * 40 + akc;
    const size_t xoff0 = (size_t)rid[ar] * HID + akc;
    const size_t xoff1 = (size_t)rid[ar + 64] * HID + akc;

    // ---- B staging (global_load_lds) ----
    const int wave = t >> 6;
    const size_t bsrc0 = (size_t)cb * 524288 + (size_t)t * 8;  // + kt*4096
    const int ldsB0 = wave * 512;          // issue 0 wave base (u16 units)
    const int ldsB1 = 2048 + wave * 512;   // issue 1

    // ---- fragment maps ----
    const int lane = t & 63;
    const int wr = wave >> 1;           // wave row half
    const int wc = wave & 1;            // wave col half
    const int fr = lane & 15;
    const int kb = lane >> 4;           // 0..3
    const int abase = (wr * 64 + fr) * 40 + kb * 8;
    const int bfrag = kb * 1024 + (wc * 64 + fr) * 8;   // + ni*128

    f32x4 acc[4][4] = {};

    // prefetch A tile 0
    float4 a00 = *(const float4*)(x + xoff0);
    float4 a01 = *(const float4*)(x + xoff0 + 4);
    float4 a10 = *(const float4*)(x + xoff1);
    float4 a11 = *(const float4*)(x + xoff1 + 4);

#pragma unroll 1
    for (int k0 = 0; k0 < HID; k0 += 32) {
        __syncthreads();
        {   // A: convert fp32 -> bf16 hi/lo, combined 16B LDS writes
            uint2 h0, l0, h1, l1;
            split4(a00, h0, l0); split4(a01, h1, l1);
            *(uint4*)&sAh[arow]  = make_uint4(h0.x, h0.y, h1.x, h1.y);
            *(uint4*)&sAl[arow]  = make_uint4(l0.x, l0.y, l1.x, l1.y);
            split4(a10, h0, l0); split4(a11, h1, l1);
            *(uint4*)&sAh[arow2] = make_uint4(h0.x, h0.y, h1.x, h1.y);
            *(uint4*)&sAl[arow2] = make_uint4(l0.x, l0.y, l1.x, l1.y);
        }
        {   // B: async direct-to-LDS, current K-tile (linear, coalesced)
            const size_t bs = bsrc0 + (size_t)(k0 >> 5) * 4096;
            gload16(wt_hi + bs,        sBh + ldsB0);
            gload16(wt_hi + bs + 2048, sBh + ldsB1);
            gload16(wt_lo + bs,        sBl + ldsB0);
            gload16(wt_lo + bs + 2048, sBl + ldsB1);
        }
        __syncthreads();   // drains vmcnt (gload_lds) + lgkm (A writes)

        if (k0 + 32 < HID) {
            a00 = *(const float4*)(x + xoff0 + k0 + 32);
            a01 = *(const float4*)(x + xoff0 + k0 + 36);
            a10 = *(const float4*)(x + xoff1 + k0 + 32);
            a11 = *(const float4*)(x + xoff1 + k0 + 36);
        }

        bf16x8 bh[4], bl[4];
#pragma unroll
        for (int ni = 0; ni < 4; ++ni) {
            bh[ni] = *(const bf16x8*)&sBh[bfrag + ni * 128];
            bl[ni] = *(const bf16x8*)&sBl[bfrag + ni * 128];
        }
#pragma unroll
        for (int mi = 0; mi < 4; ++mi) {
            const bf16x8 ah = *(const bf16x8*)&sAh[abase + mi * 640];
            const bf16x8 al = *(const bf16x8*)&sAl[abase + mi * 640];
#pragma unroll
            for (int ni = 0; ni < 4; ++ni) {
                acc[mi][ni] = __builtin_amdgcn_mfma_f32_16x16x32_bf16(ah, bh[ni], acc[mi][ni], 0, 0, 0);
                acc[mi][ni] = __builtin_amdgcn_mfma_f32_16x16x32_bf16(ah, bl[ni], acc[mi][ni], 0, 0, 0);
                acc[mi][ni] = __builtin_amdgcn_mfma_f32_16x16x32_bf16(al, bh[ni], acc[mi][ni], 0, 0, 0);
            }
        }
    }

    // ---- epilogue: LDS transpose of MFMA layout, then scores ----
    // MFMA D layout: col = lane&15, row = 4*(lane>>4)+r  (per frag)
    float* const sOut = (float*)sMem;                  // 4 waves x [16][68] f32
    float* const sW   = sOut + wave * (16 * 68);
    const int gb = (col0 >> 2) + wc * 16;              // global group base (wave)

#pragma unroll
    for (int mi = 0; mi < 4; ++mi) {
        __syncthreads();
#pragma unroll
        for (int ni = 0; ni < 4; ++ni)
#pragma unroll
            for (int r = 0; r < 4; ++r)
                sW[(kb * 4 + r) * 68 + ni * 16 + fr] = acc[mi][ni][r];
        __syncthreads();

        const int lr    = fr;                          // row 0..15
        const int gq    = kb;                          // group quad 0..3
        const int row_l = wr * 64 + mi * 16 + lr;      // local compact row
        const int cr    = row0 + row_l;
        const int orig  = rid[row_l];
        const float* so = sW + lr * 68 + gq * 16;
        const int g0    = gb + gq * 4;

        float s[4];
#pragma unroll
        for (int j = 0; j < 4; ++j) {
            const int g = g0 + j;
            const float4 lv = *(const float4*)(so + 4 * j);
            const float4 bv = *(const float4*)(bias + 4 * g);
            const float4 uv = *(const float4*)(uu + (size_t)orig * NCOLS + 4 * g);
            s[j] = score_f(lv.x + bv.x, lv.y + bv.y, lv.z + bv.z, lv.w + bv.w, uv);
        }
        *(float4*)&scoresf[(size_t)cr * NGRP + g0] = make_float4(s[0], s[1], s[2], s[3]);
    }
}

// fp32 selection with boundary-gap certification; flags close calls.
// Flagged entries packed as orig | (compact_row << 14).
__global__ __launch_bounds__(384)
void select_fast(const float* __restrict__ scoresf, const float* __restrict__ latency,
                 const int* __restrict__ idx, const int* __restrict__ count,
                 float* __restrict__ out, int* __restrict__ ridx, int* __restrict__ rcount)
{
    const int b = blockIdx.x;
    if (b >= *count) return;
    const int t = threadIdx.x;
    const int orig = idx[b];

    __shared__ __align__(16) float sm[NGRP];
    __shared__ float bnd[2];
    __shared__ int   flag;
    const float sg = scoresf[(size_t)b * NGRP + t];
    sm[t] = sg;
    if (t == 0) flag = 0;
    const int budget = budget_of(latency[orig]);   // 1..383 here
    __syncthreads();

    int rank = 0;
#pragma unroll 4
    for (int j = 0; j < NGRP; j += 4) {
        const float4 v = *(const float4*)&sm[j];
        rank += (v.x > sg || (v.x == sg && (j + 0) < t)) ? 1 : 0;
        rank += (v.y > sg || (v.y == sg && (j + 1) < t)) ? 1 : 0;
        rank += (v.z > sg || (v.z == sg && (j + 2) < t)) ? 1 : 0;
        rank += (v.w > sg || (v.w == sg && (j + 3) < t)) ? 1 : 0;
    }
    if (rank == budget - 1) bnd[0] = sg;   // min of kept set
    if (rank == budget)     bnd[1] = sg;   // max of dropped set
    __syncthreads();
    if (t == 0 && (bnd[0] - bnd[1] < GAP_MIN)) {
        flag = 1;
        ridx[atomicAdd(rcount, 1)] = orig | (b << 14);
    }
    __syncthreads();
    if (flag) return;

    const float keep = (rank < budget) ? 1.0f : 0.0f;
    float* p = out + (size_t)orig * 2048 + 512 + (size_t)(t >> 4) * 64;
    const int h2 = (t & 15) << 1;
    *(float2*)(p + h2)      = make_float2(keep, keep);
    *(float2*)(p + 32 + h2) = make_float2(1.0f - keep, 1.0f - keep);
}

// Window repair: for each flagged row, only groups whose fp32 score lies in
// [bnd1-MARG, bnd0+MARG] are uncertain (|fp32-fp64| <= ~3e-6 << MARG).
// Groups above are provably kept, below provably dropped (upper-set argument:
// cross-boundary true ordering cannot change set membership). Compute fp64
// scores ONLY for the window (usually 2 groups) and rank within it.
// Pathological windows (>WMAX) go to the full-fp64 fallback list (packed
// top-down into ridx).
__global__ __launch_bounds__(384)
void window_repair(const float* __restrict__ x, const float* __restrict__ W,
                   const float* __restrict__ bias, const float* __restrict__ u,
                   const float* __restrict__ latency, const float* __restrict__ scoresf,
                   int* __restrict__ ridx, const int* __restrict__ rcount,
                   int* __restrict__ rcount2, float* __restrict__ out)
{
    __shared__ __align__(16) float sm[NGRP];
    __shared__ float  sbnd[2];
    __shared__ double red[6][4];
    __shared__ double s64[WMAX];
    __shared__ int    wg[WMAX];
    __shared__ int    wcnt;

    const int nrep = *rcount;
    const int t = threadIdx.x;

    for (int ib = blockIdx.x; ib < nrep; ib += gridDim.x) {
        const int pk   = ridx[ib];
        const int orig = pk & 0x3FFF;
        const int row  = pk >> 14;

        const float sg = scoresf[(size_t)row * NGRP + t];
        sm[t] = sg;
        if (t == 0) wcnt = 0;
        const int budget = budget_of(latency[orig]);
        __syncthreads();

        int rank = 0;
#pragma unroll 4
        for (int j = 0; j < NGRP; j += 4) {
            const float4 v = *(const float4*)&sm[j];
            rank += (v.x > sg || (v.x == sg && (j + 0) < t)) ? 1 : 0;
            rank += (v.y > sg || (v.y == sg && (j + 1) < t)) ? 1 : 0;
            rank += (v.z > sg || (v.z == sg && (j + 2) < t)) ? 1 : 0;
            rank += (v.w > sg || (v.w == sg && (j + 3) < t)) ? 1 : 0;
        }
        if (rank == budget - 1) sbnd[0] = sg;
        if (rank == budget)     sbnd[1] = sg;
        __syncthreads();

        const float b0 = sbnd[0], b1 = sbnd[1];
        const bool hi  = sg > b0 + MARG;
        const bool lo  = sg < b1 - MARG;
        int e_t = -1;
        if (!hi && !lo) {
            e_t = atomicAdd(&wcnt, 1);
            if (e_t < WMAX) wg[e_t] = t;
        }
        const int c_hi   = __syncthreads_count(hi ? 1 : 0);
        const int wcount = wcnt;

        if (wcount > WMAX) {           // pathological: full-fp64 fallback
            if (t == 0) {
                int s2 = atomicAdd(rcount2, 1);
                ridx[16383 - s2] = pk;
            }
            __syncthreads();
            continue;
        }
        const int kwin = budget - c_hi;    // window slots to keep (>=1)

        // fp64 scores for window entries (block-cooperative dot products)
        const float* xr = x + (size_t)orig * HID;
        for (int e = 0; e < wcount; ++e) {
            const int g = wg[e];
            double p0 = 0, p1 = 0, p2 = 0, p3 = 0;
            const float* wc = W + 4 * g;
            for (int k = t; k < HID; k += 384) {
                const double xv = (double)xr[k];
                const float4 wv = *(const float4*)(wc + (size_t)k * NCOLS);
                p0 = fma(xv, (double)wv.x, p0);
                p1 = fma(xv, (double)wv.y, p1);
                p2 = fma(xv, (double)wv.z, p2);
                p3 = fma(xv, (double)wv.w, p3);
            }
#pragma unroll
            for (int off = 32; off; off >>= 1) {
                p0 += __shfl_down(p0, off);
                p1 += __shfl_down(p1, off);
                p2 += __shfl_down(p2, off);
                p3 += __shfl_down(p3, off);
            }
            const int wid = t >> 6;
            if ((t & 63) == 0) {
                red[wid][0] = p0; red[wid][1] = p1;
                red[wid][2] = p2; red[wid][3] = p3;
            }
            __syncthreads();
            if (t == 0) {
                double l0 = (double)bias[4 * g + 0], l1 = (double)bias[4 * g + 1];
                double l2 = (double)bias[4 * g + 2], l3 = (double)bias[4 * g + 3];
                for (int w = 0; w < 6; ++w) {
                    l0 += red[w][0]; l1 += red[w][1];
                    l2 += red[w][2]; l3 += red[w][3];
                }
                const float4 uv = *(const float4*)(u + (size_t)orig * NCOLS + 4 * g);
                const double d0 = ((l0 + gumbel_d(uv.x)) - (l1 + gumbel_d(uv.y))) / 5.0;
                const double d1 = ((l2 + gumbel_d(uv.z)) - (l3 + gumbel_d(uv.w))) / 5.0;
                const double q0 = 1.0 / (1.0 + exp(-d0));
                const double q1 = 1.0 / (1.0 + exp(-d1));
                s64[e] = 0.5 * (q0 + q1);
            }
            __syncthreads();
        }

        float keep;
        if (hi)      keep = 1.0f;
        else if (lo) keep = 0.0f;
        else {
            const double se = s64[e_t];
            int r = 0;
            for (int f = 0; f < wcount; ++f)
                r += (s64[f] > se || (s64[f] == se && wg[f] < t)) ? 1 : 0;
            keep = (r < kwin) ? 1.0f : 0.0f;
        }
        float* pp = out + (size_t)orig * 2048 + 512 + (size_t)(t >> 4) * 64;
        const int h2 = (t & 15) << 1;
        *(float2*)(pp + h2)      = make_float2(keep, keep);
        *(float2*)(pp + 32 + h2) = make_float2(1.0f - keep, 1.0f - keep);
        __syncthreads();   // protect sm reuse next iteration
    }
}

// fp64 FALLBACK repair GEMM over pathological rows only (list packed from
// top of ridx). Normally zero active rows.
__global__ __launch_bounds__(256)
void gemm64_repair(const float* __restrict__ x, const float* __restrict__ W,
                   const float* __restrict__ bias, const float* __restrict__ u,
                   const int* __restrict__ ridx, const int* __restrict__ rcount2,
                   double* __restrict__ scores)
{
    __shared__ float As[16][36];
    __shared__ float Bs[16][68];
    __shared__ int   rid[32];

    const int cnt  = *rcount2;
    const int row0 = blockIdx.y * 32;
    if (row0 >= cnt) return;
    const int col0 = blockIdx.x * 64;
    const int t    = threadIdx.x;

    if (t < 32) rid[t] = ridx[16383 - min(row0 + t, cnt - 1)] & 0x3FFF;
    __syncthreads();

    const bool doA = (t < 128);
    const int ar  = t >> 2;            // 0..31 when doA
    const int akc = (t & 3) << 2;
    const int bkr = t >> 4;
    const int bnc = (t & 15) << 2;

    size_t xoff = 0;
    if (doA) xoff = (size_t)rid[ar] * HID + akc;
    const float* wp = W + (size_t)bkr * NCOLS + col0 + bnc;

    const int ty = t >> 4;             // rows 2ty, 2ty+1
    const int tx = t & 15;

    double acc[2][4] = {};

    float4 a0 = make_float4(0, 0, 0, 0);
    if (doA) a0 = *(const float4*)(x + xoff);
    float4 b0 = *(const float4*)(wp);

    for (int k0 = 0; k0 < HID; k0 += 16) {
        __syncthreads();
        if (doA) {
            As[akc + 0][ar] = a0.x; As[akc + 1][ar] = a0.y;
            As[akc + 2][ar] = a0.z; As[akc + 3][ar] = a0.w;
        }
        *(float4*)&Bs[bkr][bnc] = b0;
        __syncthreads();
        if (k0 + 16 < HID) {
            if (doA) a0 = *(const float4*)(x + xoff + k0 + 16);
            b0 = *(const float4*)(wp + (size_t)(k0 + 16) * NCOLS);
        }
#pragma unroll
        for (int k = 0; k < 16; ++k) {
            const double a0d = (double)As[k][ty * 2];
            const double a1d = (double)As[k][ty * 2 + 1];
            const float4 bf  = *(const float4*)&Bs[k][tx * 4];
            const double bd[4] = {(double)bf.x, (double)bf.y, (double)bf.z, (double)bf.w};
#pragma unroll
            for (int j = 0; j < 4; ++j) {
                acc[0][j] = fma(a0d, bd[j], acc[0][j]);
                acc[1][j] = fma(a1d, bd[j], acc[1][j]);
            }
        }
    }

    const int g = (col0 >> 2) + tx;
    const double bs0 = (double)bias[4 * g + 0];
    const double bs1 = (double)bias[4 * g + 1];
    const double bs2 = (double)bias[4 * g + 2];
    const double bs3 = (double)bias[4 * g + 3];
#pragma unroll
    for (int i = 0; i < 2; ++i) {
        const int rl   = ty * 2 + i;
        const int cr   = row0 + rl;
        const int orig = rid[rl];
        const float4 uv = *(const float4*)(u + (size_t)orig * NCOLS + 4 * g);
        const double l0 = acc[i][0] + bs0;
        const double l1 = acc[i][1] + bs1;
        const double l2 = acc[i][2] + bs2;
        const double l3 = acc[i][3] + bs3;
        const double d0 = ((l0 + gumbel_d(uv.x)) - (l1 + gumbel_d(uv.y))) / 5.0;
        const double d1 = ((l2 + gumbel_d(uv.z)) - (l3 + gumbel_d(uv.w))) / 5.0;
        const double p0 = 1.0 / (1.0 + exp(-d0));
        const double p1 = 1.0 / (1.0 + exp(-d1));
        scores[(size_t)cr * NGRP + g] = 0.5 * (p0 + p1);
    }
}

// fp64 selection for fallback rows (no gap test).
__global__ __launch_bounds__(384)
void select_repair(const double* __restrict__ scores, const float* __restrict__ latency,
                   const int* __restrict__ ridx, const int* __restrict__ rcount2,
                   float* __restrict__ out)
{
    const int b = blockIdx.x;
    if (b >= *rcount2) return;
    const int t = threadIdx.x;
    const int orig = ridx[16383 - b] & 0x3FFF;

    __shared__ __align__(16) double sm[NGRP];
    const double sg = scores[(size_t)b * NGRP + t];
    sm[t] = sg;
    const int budget = budget_of(latency[orig]);
    __syncthreads();

    int rank = 0;
#pragma unroll 4
    for (int j = 0; j < NGRP; j += 2) {
        const double2 v = *(const double2*)&sm[j];
        rank += (v.x > sg || (v.x == sg && (j + 0) < t)) ? 1 : 0;
        rank += (v.y > sg || (v.y == sg && (j + 1) < t)) ? 1 : 0;
    }
    const float keep = (rank < budget) ? 1.0f : 0.0f;

    float* p = out + (size_t)orig * 2048 + 512 + (size_t)(t >> 4) * 64;
    const int h2 = (t & 15) << 1;
    *(float2*)(p + h2)      = make_float2(keep, keep);
    *(float2*)(p + 32 + h2) = make_float2(1.0f - keep, 1.0f - keep);
}

extern "C" void kernel_launch(void* const* d_in, const int* in_sizes, int n_in,
                              void* d_out, int out_size, void* d_ws, size_t ws_size,
                              hipStream_t stream) {
    const float* x       = (const float*)d_in[0];
    const float* latency = (const float*)d_in[1];
    const float* W       = (const float*)d_in[2];
    const float* bias    = (const float*)d_in[3];
    const float* u       = (const float*)d_in[4];
    float* out           = (float*)d_out;

    // ws layout (total 50,462,976 B):
    //   [count@0, rcount@4, rcount2@8 .. 256B][ridx 64KB: flagged list grows
    //   from 0, fallback list grows from top][idx 64KB is at +256 actually
    //   ordered idx then ridx as below]
    //   [WT_hi 12.58MB][WT_lo 12.58MB][scoresf 25.17MB]
    //   scores64 (fallback fp64) ALIASES [WT_hi..]: wt planes dead after
    //   gemm_bf16x3; fallback rows are few, writes stay inside dead region.
    int*    count   = (int*)d_ws;
    int*    rcount  = (int*)((char*)d_ws + 4);
    int*    rcount2 = (int*)((char*)d_ws + 8);
    int*    idx     = (int*)((char*)d_ws + 256);
    int*    ridx    = (int*)((char*)d_ws + 256 + 65536);
    u16*    wt_hi   = (u16*)((char*)d_ws + 131328);
    u16*    wt_lo   = (u16*)((char*)d_ws + 131328 + 12582912);
    float*  scoresf = (float*)((char*)d_ws + 131328 + 25165824);
    double* scores64= (double*)((char*)d_ws + 131328);

    hipMemsetAsync(d_ws, 0, 256, stream);
    convert_w<<<dim3(NCOLS / 32, HID / 32), 256, 0, stream>>>(W, wt_hi, wt_lo);
    prefilter_kernel<<<BATCH, 64, 0, stream>>>(latency, out, count, idx);
    gemm_bf16x3<<<dim3(BATCH / 128, NCOLS / 128), 256, 0, stream>>>(
        x, wt_hi, wt_lo, bias, u, idx, count, scoresf);
    select_fast<<<BATCH, NGRP, 0, stream>>>(scoresf, latency, idx, count, out, ridx, rcount);
    window_repair<<<1024, NGRP, 0, stream>>>(x, W, bias, u, latency, scoresf,
                                             ridx, rcount, rcount2, out);
    gemm64_repair<<<dim3(NCOLS / 64, BATCH / 32), 256, 0, stream>>>(
        x, W, bias, u, ridx, rcount2, scores64);
    select_repair<<<BATCH, NGRP, 0, stream>>>(scores64, latency, ridx, rcount2, out);
}

// Round 7
// 1093.500 us; speedup vs baseline: 1.8221x; 1.2702x over previous
//
#include <hip/hip_runtime.h>
#include <math.h>

// Problem constants
#define BATCH  16384
#define HID    4096
#define NCOLS  1536     // NUM_SUB * H * 2
#define NGRP   384      // NUM_SUB * H / RANK

// Gap threshold: bf16x3-path score error vs fp64 is ~2.5e-6 worst case.
#define GAP_MIN 2.0e-5f
// Certainty margin for window classification (>= 2x worst-case fp32 error).
#define MARG    1.0e-5f
#define WMAX    16

typedef unsigned short u16;
typedef short bf16x8 __attribute__((ext_vector_type(8)));
typedef float f32x4  __attribute__((ext_vector_type(4)));

__device__ __forceinline__ int budget_of(float lat) {
    float un = rintf(lat * 512.0f);           // round-half-even like jnp.round
    un = fminf(fmaxf(un, 128.0f), 512.0f);
    return (int)un - 128;                     // 0..384
}

__device__ __forceinline__ double gumbel_d(float uu) {
    double v = (double)uu * (1.0 - 2.0e-6) + 1.0e-6;
    return -log(-log(v));
}

// fp32 gumbel, accurate at BOTH tails.
__device__ __forceinline__ float gumbel_f(float u) {
    float inner;
    if (u <= 0.5f) {
        float v = fmaf(u, 0.999998f, 1e-6f);          // u*(1-2e-6)+1e-6
        inner = -logf(v);
    } else {
        float t1 = 1.0f - u;                          // exact
        float w  = fmaf(1e-6f, fmaf(2.0f, u, -1.0f), t1);
        inner = -log1pf(-w);
    }
    return -logf(inner);
}

__device__ __forceinline__ float score_f(float l0, float l1, float l2, float l3,
                                         float4 uv) {
    const float d0 = ((l0 + gumbel_f(uv.x)) - (l1 + gumbel_f(uv.y))) * 0.2f;
    const float d1 = ((l2 + gumbel_f(uv.z)) - (l3 + gumbel_f(uv.w))) * 0.2f;
    const float p0 = 1.0f / (1.0f + expf(-d0));
    const float p1 = 1.0f / (1.0f + expf(-d1));
    return 0.5f * (p0 + p1);
}

// ---- bf16 split helpers ----
__device__ __forceinline__ unsigned bf16_rne_bits(float f) {
    unsigned b = __float_as_uint(f);
    return (b + 0x7FFFu + ((b >> 16) & 1u)) >> 16;
}

// Hot-path split: hi = RTZ-bf16 (bitmask), lo = RNE-bf16(x - hi).
__device__ __forceinline__ void split4(const float4 v, uint2& hi, uint2& lo) {
    const unsigned bx = __float_as_uint(v.x), by = __float_as_uint(v.y),
                   bz = __float_as_uint(v.z), bw = __float_as_uint(v.w);
    const unsigned hx = bx & 0xFFFF0000u, hy = by & 0xFFFF0000u,
                   hz = bz & 0xFFFF0000u, hw = bw & 0xFFFF0000u;
    hi.x = (hx >> 16) | hy;
    hi.y = (hz >> 16) | hw;
    const float lx = v.x - __uint_as_float(hx);
    const float ly = v.y - __uint_as_float(hy);
    const float lz = v.z - __uint_as_float(hz);
    const float lw = v.w - __uint_as_float(hw);
    lo.x = bf16_rne_bits(lx) | (bf16_rne_bits(ly) << 16);
    lo.y = bf16_rne_bits(lz) | (bf16_rne_bits(lw) << 16);
}

// Async global->LDS, 16B per lane. LDS dest is wave-uniform base + lane*16.
__device__ __forceinline__ void gload16(const u16* g, u16* l) {
    __builtin_amdgcn_global_load_lds(
        (const __attribute__((address_space(1))) unsigned int*)g,
        (__attribute__((address_space(3))) unsigned int*)l, 16, 0, 0);
}

// Trivial-output fill + prefix fill. NO atomics (r5 post-mortem: ~12.3k
// serialized same-address device atomics suspected as a hidden ~100-500us).
__global__ __launch_bounds__(64)
void prefilter_kernel(const float* __restrict__ latency, float* __restrict__ out)
{
    const int b = blockIdx.x;
    const int t = threadIdx.x;
    const int budget = budget_of(latency[b]);
    float* obase = out + (size_t)b * 2048;

    const float4 ones = make_float4(1.f, 1.f, 1.f, 1.f);
    ((float4*)obase)[t]      = ones;   // prefix: layers 0..7 all ones
    ((float4*)obase)[t + 64] = ones;

    if (!(budget > 0 && budget < NGRP)) {
        const float K = (budget == 0) ? 0.0f : 1.0f;
#pragma unroll
        for (int j = 0; j < 6; ++j) {
            const int i = j * 64 + t;
            const int p = i * 4;             // p = l*64 + s*32 + h
            const int s = (p >> 5) & 1;
            const float v = s ? (1.0f - K) : K;
            ((float4*)(obase + 512))[i] = make_float4(v, v, v, v);
        }
    }
}

// Wave-aggregated compaction of interior rows: 1 atomic per wave (256 total).
__global__ __launch_bounds__(256)
void idx_build(const float* __restrict__ latency, int* __restrict__ count,
               int* __restrict__ idx)
{
    const int s = blockIdx.x * 256 + threadIdx.x;
    const int budget = budget_of(latency[s]);
    const bool interior = (budget > 0 && budget < NGRP);
    const unsigned long long m = __ballot(interior);
    const int lane = threadIdx.x & 63;
    int base = 0;
    if (lane == 0 && m) base = atomicAdd(count, __popcll(m));
    base = __shfl(base, 0);
    if (interior)
        idx[base + __popcll(m & ((1ull << lane) - 1ull))] = s;
}

// One-time W transpose + bf16 hi/lo split into a kb-major TILED layout:
//   wt[colblk 12][ktile 128][kb 4][n 128][e 8]  (u16)
__global__ __launch_bounds__(256)
void convert_w(const float* __restrict__ W, u16* __restrict__ wt_hi,
               u16* __restrict__ wt_lo)
{
    __shared__ float sT[32][33];
    const int n0 = blockIdx.x * 32, k0 = blockIdx.y * 32;
    const int t  = threadIdx.x;
    {
        const int lr = t >> 3, lc = (t & 7) * 4;
        const float4 v = *(const float4*)(W + (size_t)(k0 + lr) * NCOLS + n0 + lc);
        sT[lr][lc] = v.x; sT[lr][lc + 1] = v.y; sT[lr][lc + 2] = v.z; sT[lr][lc + 3] = v.w;
    }
    __syncthreads();
    const int ln = t >> 3, lk = (t & 7) * 4;     // ln: n-local, lk: k-local
    unsigned hb[4], lb[4];
#pragma unroll
    for (int j = 0; j < 4; ++j) {
        const float xv = sT[lk + j][ln];
        const unsigned h = bf16_rne_bits(xv);          // RNE hi for W (one-time)
        const float hf = __uint_as_float(h << 16);
        hb[j] = h;
        lb[j] = bf16_rne_bits(xv - hf);
    }
    uint2 hw, lw;
    hw.x = hb[0] | (hb[1] << 16); hw.y = hb[2] | (hb[3] << 16);
    lw.x = lb[0] | (lb[1] << 16); lw.y = lb[2] | (lb[3] << 16);
    const int gn = n0 + ln;
    const size_t off = ((size_t)((gn >> 7) * 128 + (k0 >> 5)) * 4 + (lk >> 3)) * 1024
                     + (size_t)(gn & 127) * 8 + (lk & 7);
    *(uint2*)(wt_hi + off) = hw;
    *(uint2*)(wt_lo + off) = lw;
}

// bf16x3 MFMA GEMM (128x128 tile, BK=32) + fp32 gumbel-softmax scores.
// r3-proven single-buffer 2-barrier structure (explicit dbuf REGRESSED in r4:
// LDS 74KB + VGPR 100 cut occupancy 26->19%, 618->1034 us — trap #5).
// Grid is (rb=128, cb=12): blocks sharing an x row-panel land on one XCD.
// NOTE: every access to acc[][] must be compile-time-indexed (full unroll).
__global__ __launch_bounds__(256)
void gemm_bf16x3(const float* __restrict__ x, const u16* __restrict__ wt_hi,
                 const u16* __restrict__ wt_lo, const float* __restrict__ bias,
                 const float* __restrict__ uu, const int* __restrict__ idx,
                 const int* __restrict__ count, float* __restrict__ scoresf)
{
    // A planes: [128][40] u16 (pad->80B rows, 2-way banks = free)
    // B planes: [4 kb][128 n][8 e] u16 linear (gload_lds dest; reads 2-way free)
    __shared__ __align__(16) u16 sMem[2 * 5120 + 2 * 4096];   // 36864 B
    __shared__ int rid[128];
    u16* const sAh = sMem;
    u16* const sAl = sMem + 5120;
    u16* const sBh = sMem + 10240;
    u16* const sBl = sMem + 14336;

    const int cnt  = *count;
    const int row0 = blockIdx.x * 128;
    if (row0 >= cnt) return;
    const int cb   = blockIdx.y;
    const int col0 = cb * 128;
    const int t    = threadIdx.x;

    if (t < 128) rid[t] = idx[min(row0 + t, cnt - 1)];
    __syncthreads();

    // ---- A staging maps ----
    const int ar  = t >> 2;             // A rows ar and ar+64
    const int akc = (t & 3) << 3;       // k offset {0,8,16,24}
    const int arow  = ar * 40 + akc;
    const int arow2 = (ar + 64) * 40 + akc;
    const size_t xoff0 = (size_t)rid[ar] * HID + akc;
    const size_t xoff1 = (size_t)rid[ar + 64] * HID + akc;

    // ---- B staging (global_load_lds) ----
    const int wave = t >> 6;
    const size_t bsrc0 = (size_t)cb * 524288 + (size_t)t * 8;  // + kt*4096
    const int ldsB0 = wave * 512;          // issue 0 wave base (u16 units)
    const int ldsB1 = 2048 + wave * 512;   // issue 1

    // ---- fragment maps ----
    const int lane = t & 63;
    const int wr = wave >> 1;           // wave row half
    const int wc = wave & 1;            // wave col half
    const int fr = lane & 15;
    const int kb = lane >> 4;           // 0..3
    const int abase = (wr * 64 + fr) * 40 + kb * 8;
    const int bfrag = kb * 1024 + (wc * 64 + fr) * 8;   // + ni*128

    f32x4 acc[4][4] = {};

    // prefetch A tile 0
    float4 a00 = *(const float4*)(x + xoff0);
    float4 a01 = *(const float4*)(x + xoff0 + 4);
    float4 a10 = *(const float4*)(x + xoff1);
    float4 a11 = *(const float4*)(x + xoff1 + 4);

#pragma unroll 1
    for (int k0 = 0; k0 < HID; k0 += 32) {
        __syncthreads();
        {   // A: convert fp32 -> bf16 hi/lo, combined 16B LDS writes
            uint2 h0, l0, h1, l1;
            split4(a00, h0, l0); split4(a01, h1, l1);
            *(uint4*)&sAh[arow]  = make_uint4(h0.x, h0.y, h1.x, h1.y);
            *(uint4*)&sAl[arow]  = make_uint4(l0.x, l0.y, l1.x, l1.y);
            split4(a10, h0, l0); split4(a11, h1, l1);
            *(uint4*)&sAh[arow2] = make_uint4(h0.x, h0.y, h1.x, h1.y);
            *(uint4*)&sAl[arow2] = make_uint4(l0.x, l0.y, l1.x, l1.y);
        }
        {   // B: async direct-to-LDS, current K-tile (linear, coalesced)
            const size_t bs = bsrc0 + (size_t)(k0 >> 5) * 4096;
            gload16(wt_hi + bs,        sBh + ldsB0);
            gload16(wt_hi + bs + 2048, sBh + ldsB1);
            gload16(wt_lo + bs,        sBl + ldsB0);
            gload16(wt_lo + bs + 2048, sBl + ldsB1);
        }
        __syncthreads();   // drains vmcnt (gload_lds) + lgkm (A writes)

        if (k0 + 32 < HID) {
            a00 = *(const float4*)(x + xoff0 + k0 + 32);
            a01 = *(const float4*)(x + xoff0 + k0 + 36);
            a10 = *(const float4*)(x + xoff1 + k0 + 32);
            a11 = *(const float4*)(x + xoff1 + k0 + 36);
        }

        bf16x8 bh[4], bl[4];
#pragma unroll
        for (int ni = 0; ni < 4; ++ni) {
            bh[ni] = *(const bf16x8*)&sBh[bfrag + ni * 128];
            bl[ni] = *(const bf16x8*)&sBl[bfrag + ni * 128];
        }
#pragma unroll
        for (int mi = 0; mi < 4; ++mi) {
            const bf16x8 ah = *(const bf16x8*)&sAh[abase + mi * 640];
            const bf16x8 al = *(const bf16x8*)&sAl[abase + mi * 640];
#pragma unroll
            for (int ni = 0; ni < 4; ++ni) {
                acc[mi][ni] = __builtin_amdgcn_mfma_f32_16x16x32_bf16(ah, bh[ni], acc[mi][ni], 0, 0, 0);
                acc[mi][ni] = __builtin_amdgcn_mfma_f32_16x16x32_bf16(ah, bl[ni], acc[mi][ni], 0, 0, 0);
                acc[mi][ni] = __builtin_amdgcn_mfma_f32_16x16x32_bf16(al, bh[ni], acc[mi][ni], 0, 0, 0);
            }
        }
    }

    // ---- epilogue: LDS transpose of MFMA layout, then scores ----
    // MFMA D layout: col = lane&15, row = 4*(lane>>4)+r  (per frag)
    float* const sOut = (float*)sMem;                  // 4 waves x [16][68] f32
    float* const sW   = sOut + wave * (16 * 68);
    const int gb = (col0 >> 2) + wc * 16;              // global group base (wave)

#pragma unroll
    for (int mi = 0; mi < 4; ++mi) {
        __syncthreads();
#pragma unroll
        for (int ni = 0; ni < 4; ++ni)
#pragma unroll
            for (int r = 0; r < 4; ++r)
                sW[(kb * 4 + r) * 68 + ni * 16 + fr] = acc[mi][ni][r];
        __syncthreads();

        const int lr    = fr;                          // row 0..15
        const int gq    = kb;                          // group quad 0..3
        const int row_l = wr * 64 + mi * 16 + lr;      // local compact row
        const int cr    = row0 + row_l;
        const int orig  = rid[row_l];
        const float* so = sW + lr * 68 + gq * 16;
        const int g0    = gb + gq * 4;

        float s[4];
#pragma unroll
        for (int j = 0; j < 4; ++j) {
            const int g = g0 + j;
            const float4 lv = *(const float4*)(so + 4 * j);
            const float4 bv = *(const float4*)(bias + 4 * g);
            const float4 uv = *(const float4*)(uu + (size_t)orig * NCOLS + 4 * g);
            s[j] = score_f(lv.x + bv.x, lv.y + bv.y, lv.z + bv.z, lv.w + bv.w, uv);
        }
        *(float4*)&scoresf[(size_t)cr * NGRP + g0] = make_float4(s[0], s[1], s[2], s[3]);
    }
}

// fp32 selection, u32-bit ranking (positive floats: bit compare == value
// compare; 2 VALU/elem vs ~7 for the float+tie chain). Index tie-breaks only
// matter when EXACTLY-equal values straddle the cut — detected exactly by
// count(kept) != budget -> full-fp64 fallback (probability ~0). Otherwise
// kept = {rank < budget} is exact; boundary values via block min/max.
// Small-gap rows -> window repair. Flagged entries: orig | (row << 14).
__global__ __launch_bounds__(384)
void select_fast(const float* __restrict__ scoresf, const float* __restrict__ latency,
                 const int* __restrict__ idx, const int* __restrict__ count,
                 float* __restrict__ out, int* __restrict__ ridx,
                 int* __restrict__ rcount, int* __restrict__ rcount2)
{
    const int b = blockIdx.x;
    if (b >= *count) return;
    const int t = threadIdx.x;
    const int orig = idx[b];

    __shared__ __align__(16) unsigned smu[NGRP];
    __shared__ float wred0[6], wred1[6];
    __shared__ int   flag;
    const float sg = scoresf[(size_t)b * NGRP + t];
    const unsigned bg = __float_as_uint(sg);
    smu[t] = bg;
    if (t == 0) flag = 0;
    const int budget = budget_of(latency[orig]);   // 1..383 here
    __syncthreads();

    int rank = 0;
#pragma unroll 4
    for (int j = 0; j < NGRP; j += 4) {
        const uint4 v = *(const uint4*)&smu[j];
        rank += (v.x > bg) ? 1 : 0;
        rank += (v.y > bg) ? 1 : 0;
        rank += (v.z > bg) ? 1 : 0;
        rank += (v.w > bg) ? 1 : 0;
    }
    const bool kept = (rank < budget);
    const int  ck   = __syncthreads_count(kept ? 1 : 0);

    if (ck != budget) {        // exact-tie straddle at the cut: fp64 fallback
        if (t == 0) { int s2 = atomicAdd(rcount2, 1); ridx[16383 - s2] = orig | (b << 14); }
        return;
    }

    float kv = kept ? sg : 3.0e38f;     // min over kept  -> bnd0
    float dv = kept ? -3.0e38f : sg;    // max over dropped -> bnd1
#pragma unroll
    for (int off = 32; off; off >>= 1) {
        kv = fminf(kv, __shfl_xor(kv, off));
        dv = fmaxf(dv, __shfl_xor(dv, off));
    }
    if ((t & 63) == 0) { wred0[t >> 6] = kv; wred1[t >> 6] = dv; }
    __syncthreads();
    if (t == 0) {
        float b0 = wred0[0], b1 = wred1[0];
#pragma unroll
        for (int w = 1; w < 6; ++w) { b0 = fminf(b0, wred0[w]); b1 = fmaxf(b1, wred1[w]); }
        if (b0 - b1 < GAP_MIN) { flag = 1; ridx[atomicAdd(rcount, 1)] = orig | (b << 14); }
    }
    __syncthreads();
    if (flag) return;

    const float keep = kept ? 1.0f : 0.0f;
    float* p = out + (size_t)orig * 2048 + 512 + (size_t)(t >> 4) * 64;
    const int h2 = (t & 15) << 1;
    *(float2*)(p + h2)      = make_float2(keep, keep);
    *(float2*)(p + 32 + h2) = make_float2(1.0f - keep, 1.0f - keep);
}

// Window repair: for each flagged row, only groups whose fp32 score lies in
// [bnd1-MARG, bnd0+MARG] are uncertain (|fp32-fp64| <= ~3e-6 << MARG).
// fp64 scores ONLY for the window (usually 2 groups), ranked within it.
// Pathological rows (window > WMAX, or exact-tie straddle) -> fp64 fallback.
__global__ __launch_bounds__(384)
void window_repair(const float* __restrict__ x, const float* __restrict__ W,
                   const float* __restrict__ bias, const float* __restrict__ u,
                   const float* __restrict__ latency, const float* __restrict__ scoresf,
                   int* __restrict__ ridx, const int* __restrict__ rcount,
                   int* __restrict__ rcount2, float* __restrict__ out)
{
    __shared__ __align__(16) unsigned smu[NGRP];
    __shared__ float  wred0[6], wred1[6];
    __shared__ float  sbnd[2];
    __shared__ double red[6][4];
    __shared__ double s64[WMAX];
    __shared__ int    wg[WMAX];
    __shared__ int    wcnt;

    const int nrep = *rcount;
    const int t = threadIdx.x;

    for (int ib = blockIdx.x; ib < nrep; ib += gridDim.x) {
        const int pk   = ridx[ib];
        const int orig = pk & 0x3FFF;
        const int row  = pk >> 14;

        const float sg = scoresf[(size_t)row * NGRP + t];
        const unsigned bg = __float_as_uint(sg);
        smu[t] = bg;
        if (t == 0) wcnt = 0;
        const int budget = budget_of(latency[orig]);
        __syncthreads();

        int rank = 0;
#pragma unroll 4
        for (int j = 0; j < NGRP; j += 4) {
            const uint4 v = *(const uint4*)&smu[j];
            rank += (v.x > bg) ? 1 : 0;
            rank += (v.y > bg) ? 1 : 0;
            rank += (v.z > bg) ? 1 : 0;
            rank += (v.w > bg) ? 1 : 0;
        }
        const bool kept = (rank < budget);
        const int  ck   = __syncthreads_count(kept ? 1 : 0);

        if (ck != budget) {            // straddle: fp64 fallback
            if (t == 0) { int s2 = atomicAdd(rcount2, 1); ridx[16383 - s2] = pk; }
            __syncthreads();
            continue;
        }
        float kv = kept ? sg : 3.0e38f;
        float dv = kept ? -3.0e38f : sg;
#pragma unroll
        for (int off = 32; off; off >>= 1) {
            kv = fminf(kv, __shfl_xor(kv, off));
            dv = fmaxf(dv, __shfl_xor(dv, off));
        }
        if ((t & 63) == 0) { wred0[t >> 6] = kv; wred1[t >> 6] = dv; }
        __syncthreads();
        if (t == 0) {
            float v0 = wred0[0], v1 = wred1[0];
#pragma unroll
            for (int w = 1; w < 6; ++w) { v0 = fminf(v0, wred0[w]); v1 = fmaxf(v1, wred1[w]); }
            sbnd[0] = v0; sbnd[1] = v1;
        }
        __syncthreads();

        const float b0 = sbnd[0], b1 = sbnd[1];
        const bool hi  = sg > b0 + MARG;
        const bool lo  = sg < b1 - MARG;
        int e_t = -1;
        if (!hi && !lo) {
            e_t = atomicAdd(&wcnt, 1);
            if (e_t < WMAX) wg[e_t] = t;
        }
        const int c_hi   = __syncthreads_count(hi ? 1 : 0);
        const int wcount = wcnt;

        if (wcount > WMAX) {           // pathological: full-fp64 fallback
            if (t == 0) { int s2 = atomicAdd(rcount2, 1); ridx[16383 - s2] = pk; }
            __syncthreads();
            continue;
        }
        const int kwin = budget - c_hi;    // window slots to keep (>=1)

        // fp64 scores for window entries (block-cooperative dot products)
        const float* xr = x + (size_t)orig * HID;
        for (int e = 0; e < wcount; ++e) {
            const int g = wg[e];
            double p0 = 0, p1 = 0, p2 = 0, p3 = 0;
            const float* wcp = W + 4 * g;
            for (int k = t; k < HID; k += 384) {
                const double xv = (double)xr[k];
                const float4 wv = *(const float4*)(wcp + (size_t)k * NCOLS);
                p0 = fma(xv, (double)wv.x, p0);
                p1 = fma(xv, (double)wv.y, p1);
                p2 = fma(xv, (double)wv.z, p2);
                p3 = fma(xv, (double)wv.w, p3);
            }
#pragma unroll
            for (int off = 32; off; off >>= 1) {
                p0 += __shfl_down(p0, off);
                p1 += __shfl_down(p1, off);
                p2 += __shfl_down(p2, off);
                p3 += __shfl_down(p3, off);
            }
            const int wid = t >> 6;
            if ((t & 63) == 0) {
                red[wid][0] = p0; red[wid][1] = p1;
                red[wid][2] = p2; red[wid][3] = p3;
            }
            __syncthreads();
            if (t == 0) {
                double l0 = (double)bias[4 * g + 0], l1 = (double)bias[4 * g + 1];
                double l2 = (double)bias[4 * g + 2], l3 = (double)bias[4 * g + 3];
                for (int w = 0; w < 6; ++w) {
                    l0 += red[w][0]; l1 += red[w][1];
                    l2 += red[w][2]; l3 += red[w][3];
                }
                const float4 uv = *(const float4*)(u + (size_t)orig * NCOLS + 4 * g);
                const double d0 = ((l0 + gumbel_d(uv.x)) - (l1 + gumbel_d(uv.y))) / 5.0;
                const double d1 = ((l2 + gumbel_d(uv.z)) - (l3 + gumbel_d(uv.w))) / 5.0;
                const double q0 = 1.0 / (1.0 + exp(-d0));
                const double q1 = 1.0 / (1.0 + exp(-d1));
                s64[e] = 0.5 * (q0 + q1);
            }
            __syncthreads();
        }

        float keep;
        if (hi)      keep = 1.0f;
        else if (lo) keep = 0.0f;
        else {
            const double se = s64[e_t];
            int r = 0;
            for (int f = 0; f < wcount; ++f)
                r += (s64[f] > se || (s64[f] == se && wg[f] < t)) ? 1 : 0;
            keep = (r < kwin) ? 1.0f : 0.0f;
        }
        float* pp = out + (size_t)orig * 2048 + 512 + (size_t)(t >> 4) * 64;
        const int h2 = (t & 15) << 1;
        *(float2*)(pp + h2)      = make_float2(keep, keep);
        *(float2*)(pp + 32 + h2) = make_float2(1.0f - keep, 1.0f - keep);
        __syncthreads();   // protect smu reuse next iteration
    }
}

// fp64 FALLBACK repair GEMM over pathological rows only (list packed from
// top of ridx). Normally zero active rows.
__global__ __launch_bounds__(256)
void gemm64_repair(const float* __restrict__ x, const float* __restrict__ W,
                   const float* __restrict__ bias, const float* __restrict__ u,
                   const int* __restrict__ ridx, const int* __restrict__ rcount2,
                   double* __restrict__ scores)
{
    __shared__ float As[16][36];
    __shared__ float Bs[16][68];
    __shared__ int   rid[32];

    const int cnt  = *rcount2;
    const int row0 = blockIdx.y * 32;
    if (row0 >= cnt) return;
    const int col0 = blockIdx.x * 64;
    const int t    = threadIdx.x;

    if (t < 32) rid[t] = ridx[16383 - min(row0 + t, cnt - 1)] & 0x3FFF;
    __syncthreads();

    const bool doA = (t < 128);
    const int ar  = t >> 2;            // 0..31 when doA
    const int akc = (t & 3) << 2;
    const int bkr = t >> 4;
    const int bnc = (t & 15) << 2;

    size_t xoff = 0;
    if (doA) xoff = (size_t)rid[ar] * HID + akc;
    const float* wp = W + (size_t)bkr * NCOLS + col0 + bnc;

    const int ty = t >> 4;             // rows 2ty, 2ty+1
    const int tx = t & 15;

    double acc[2][4] = {};

    float4 a0 = make_float4(0, 0, 0, 0);
    if (doA) a0 = *(const float4*)(x + xoff);
    float4 b0 = *(const float4*)(wp);

    for (int k0 = 0; k0 < HID; k0 += 16) {
        __syncthreads();
        if (doA) {
            As[akc + 0][ar] = a0.x; As[akc + 1][ar] = a0.y;
            As[akc + 2][ar] = a0.z; As[akc + 3][ar] = a0.w;
        }
        *(float4*)&Bs[bkr][bnc] = b0;
        __syncthreads();
        if (k0 + 16 < HID) {
            if (doA) a0 = *(const float4*)(x + xoff + k0 + 16);
            b0 = *(const float4*)(wp + (size_t)(k0 + 16) * NCOLS);
        }
#pragma unroll
        for (int k = 0; k < 16; ++k) {
            const double a0d = (double)As[k][ty * 2];
            const double a1d = (double)As[k][ty * 2 + 1];
            const float4 bf  = *(const float4*)&Bs[k][tx * 4];
            const double bd[4] = {(double)bf.x, (double)bf.y, (double)bf.z, (double)bf.w};
#pragma unroll
            for (int j = 0; j < 4; ++j) {
                acc[0][j] = fma(a0d, bd[j], acc[0][j]);
                acc[1][j] = fma(a1d, bd[j], acc[1][j]);
            }
        }
    }

    const int g = (col0 >> 2) + tx;
    const double bs0 = (double)bias[4 * g + 0];
    const double bs1 = (double)bias[4 * g + 1];
    const double bs2 = (double)bias[4 * g + 2];
    const double bs3 = (double)bias[4 * g + 3];
#pragma unroll
    for (int i = 0; i < 2; ++i) {
        const int rl   = ty * 2 + i;
        const int cr   = row0 + rl;
        const int orig = rid[rl];
        const float4 uv = *(const float4*)(u + (size_t)orig * NCOLS + 4 * g);
        const double l0 = acc[i][0] + bs0;
        const double l1 = acc[i][1] + bs1;
        const double l2 = acc[i][2] + bs2;
        const double l3 = acc[i][3] + bs3;
        const double d0 = ((l0 + gumbel_d(uv.x)) - (l1 + gumbel_d(uv.y))) / 5.0;
        const double d1 = ((l2 + gumbel_d(uv.z)) - (l3 + gumbel_d(uv.w))) / 5.0;
        const double p0 = 1.0 / (1.0 + exp(-d0));
        const double p1 = 1.0 / (1.0 + exp(-d1));
        scores[(size_t)cr * NGRP + g] = 0.5 * (p0 + p1);
    }
}

// fp64 selection for fallback rows (exact, with index tie-break).
__global__ __launch_bounds__(384)
void select_repair(const double* __restrict__ scores, const float* __restrict__ latency,
                   const int* __restrict__ ridx, const int* __restrict__ rcount2,
                   float* __restrict__ out)
{
    const int b = blockIdx.x;
    if (b >= *rcount2) return;
    const int t = threadIdx.x;
    const int orig = ridx[16383 - b] & 0x3FFF;

    __shared__ __align__(16) double sm[NGRP];
    const double sg = scores[(size_t)b * NGRP + t];
    sm[t] = sg;
    const int budget = budget_of(latency[orig]);
    __syncthreads();

    int rank = 0;
#pragma unroll 4
    for (int j = 0; j < NGRP; j += 2) {
        const double2 v = *(const double2*)&sm[j];
        rank += (v.x > sg || (v.x == sg && (j + 0) < t)) ? 1 : 0;
        rank += (v.y > sg || (v.y == sg && (j + 1) < t)) ? 1 : 0;
    }
    const float keep = (rank < budget) ? 1.0f : 0.0f;

    float* p = out + (size_t)orig * 2048 + 512 + (size_t)(t >> 4) * 64;
    const int h2 = (t & 15) << 1;
    *(float2*)(p + h2)      = make_float2(keep, keep);
    *(float2*)(p + 32 + h2) = make_float2(1.0f - keep, 1.0f - keep);
}

extern "C" void kernel_launch(void* const* d_in, const int* in_sizes, int n_in,
                              void* d_out, int out_size, void* d_ws, size_t ws_size,
                              hipStream_t stream) {
    const float* x       = (const float*)d_in[0];
    const float* latency = (const float*)d_in[1];
    const float* W       = (const float*)d_in[2];
    const float* bias    = (const float*)d_in[3];
    const float* u       = (const float*)d_in[4];
    float* out           = (float*)d_out;

    // ws layout (total 50,462,976 B):
    //   [count@0, rcount@4, rcount2@8 .. 256B][idx 64KB][ridx 64KB: window
    //   list grows from 0, fallback list grows from index 16383 down]
    //   [WT_hi 12.58MB][WT_lo 12.58MB][scoresf 25.17MB]
    //   scores64 (fallback fp64) ALIASES [WT_hi..]: wt planes dead after
    //   gemm_bf16x3; fallback rows are few, writes stay inside dead region.
    int*    count   = (int*)d_ws;
    int*    rcount  = (int*)((char*)d_ws + 4);
    int*    rcount2 = (int*)((char*)d_ws + 8);
    int*    idx     = (int*)((char*)d_ws + 256);
    int*    ridx    = (int*)((char*)d_ws + 256 + 65536);
    u16*    wt_hi   = (u16*)((char*)d_ws + 131328);
    u16*    wt_lo   = (u16*)((char*)d_ws + 131328 + 12582912);
    float*  scoresf = (float*)((char*)d_ws + 131328 + 25165824);
    double* scores64= (double*)((char*)d_ws + 131328);

    hipMemsetAsync(d_ws, 0, 256, stream);
    convert_w<<<dim3(NCOLS / 32, HID / 32), 256, 0, stream>>>(W, wt_hi, wt_lo);
    prefilter_kernel<<<BATCH, 64, 0, stream>>>(latency, out);
    idx_build<<<BATCH / 256, 256, 0, stream>>>(latency, count, idx);
    gemm_bf16x3<<<dim3(BATCH / 128, NCOLS / 128), 256, 0, stream>>>(
        x, wt_hi, wt_lo, bias, u, idx, count, scoresf);
    select_fast<<<BATCH, NGRP, 0, stream>>>(scoresf, latency, idx, count, out,
                                            ridx, rcount, rcount2);
    window_repair<<<1024, NGRP, 0, stream>>>(x, W, bias, u, latency, scoresf,
                                             ridx, rcount, rcount2, out);
    gemm64_repair<<<dim3(NCOLS / 64, BATCH / 32), 256, 0, stream>>>(
        x, W, bias, u, ridx, rcount2, scores64);
    select_repair<<<BATCH, NGRP, 0, stream>>>(scores64, latency, ridx, rcount2, out);
}

// Round 8
// 1042.721 us; speedup vs baseline: 1.9108x; 1.0487x over previous
//
#include <hip/hip_runtime.h>
#include <math.h>

// Problem constants
#define BATCH  16384
#define HID    4096
#define NCOLS  1536     // NUM_SUB * H * 2
#define NGRP   384      // NUM_SUB * H / RANK

// Gap threshold: bf16x3-path score error vs fp64 is ~2.5e-6 worst case.
#define GAP_MIN 2.0e-5f
// Certainty margin for window classification (>= 2x worst-case fp32 error).
#define MARG    1.0e-5f
#define WMAX    16

typedef unsigned short u16;
typedef short bf16x8 __attribute__((ext_vector_type(8)));
typedef float f32x4  __attribute__((ext_vector_type(4)));

__device__ __forceinline__ int budget_of(float lat) {
    float un = rintf(lat * 512.0f);           // round-half-even like jnp.round
    un = fminf(fmaxf(un, 128.0f), 512.0f);
    return (int)un - 128;                     // 0..384
}

__device__ __forceinline__ double gumbel_d(float uu) {
    double v = (double)uu * (1.0 - 2.0e-6) + 1.0e-6;
    return -log(-log(v));
}

// fp32 gumbel, accurate at BOTH tails.
__device__ __forceinline__ float gumbel_f(float u) {
    float inner;
    if (u <= 0.5f) {
        float v = fmaf(u, 0.999998f, 1e-6f);          // u*(1-2e-6)+1e-6
        inner = -logf(v);
    } else {
        float t1 = 1.0f - u;                          // exact
        float w  = fmaf(1e-6f, fmaf(2.0f, u, -1.0f), t1);
        inner = -log1pf(-w);
    }
    return -logf(inner);
}

__device__ __forceinline__ float score_f(float l0, float l1, float l2, float l3,
                                         float4 uv) {
    const float d0 = ((l0 + gumbel_f(uv.x)) - (l1 + gumbel_f(uv.y))) * 0.2f;
    const float d1 = ((l2 + gumbel_f(uv.z)) - (l3 + gumbel_f(uv.w))) * 0.2f;
    const float p0 = 1.0f / (1.0f + expf(-d0));
    const float p1 = 1.0f / (1.0f + expf(-d1));
    return 0.5f * (p0 + p1);
}

// ---- bf16 split helpers ----
__device__ __forceinline__ unsigned bf16_rne_bits(float f) {
    unsigned b = __float_as_uint(f);
    return (b + 0x7FFFu + ((b >> 16) & 1u)) >> 16;
}

// Hot-path split: hi = RTZ-bf16 (bitmask), lo = RNE-bf16(x - hi).
__device__ __forceinline__ void split4(const float4 v, uint2& hi, uint2& lo) {
    const unsigned bx = __float_as_uint(v.x), by = __float_as_uint(v.y),
                   bz = __float_as_uint(v.z), bw = __float_as_uint(v.w);
    const unsigned hx = bx & 0xFFFF0000u, hy = by & 0xFFFF0000u,
                   hz = bz & 0xFFFF0000u, hw = bw & 0xFFFF0000u;
    hi.x = (hx >> 16) | hy;
    hi.y = (hz >> 16) | hw;
    const float lx = v.x - __uint_as_float(hx);
    const float ly = v.y - __uint_as_float(hy);
    const float lz = v.z - __uint_as_float(hz);
    const float lw = v.w - __uint_as_float(hw);
    lo.x = bf16_rne_bits(lx) | (bf16_rne_bits(ly) << 16);
    lo.y = bf16_rne_bits(lz) | (bf16_rne_bits(lw) << 16);
}

// Async global->LDS, 16B per lane. LDS dest is wave-uniform base + lane*16.
__device__ __forceinline__ void gload16(const u16* g, u16* l) {
    __builtin_amdgcn_global_load_lds(
        (const __attribute__((address_space(1))) unsigned int*)g,
        (__attribute__((address_space(3))) unsigned int*)l, 16, 0, 0);
}

// Trivial-output fill + prefix fill. 4 samples per 256-thread block.
__global__ __launch_bounds__(256)
void prefilter_kernel(const float* __restrict__ latency, float* __restrict__ out)
{
    const int b = blockIdx.x * 4 + (threadIdx.x >> 6);
    const int lane = threadIdx.x & 63;
    const int budget = budget_of(latency[b]);
    float* obase = out + (size_t)b * 2048;

    const float4 ones = make_float4(1.f, 1.f, 1.f, 1.f);
    ((float4*)obase)[lane]      = ones;   // prefix: layers 0..7 all ones
    ((float4*)obase)[lane + 64] = ones;

    if (!(budget > 0 && budget < NGRP)) {
        const float K = (budget == 0) ? 0.0f : 1.0f;
#pragma unroll
        for (int j = 0; j < 6; ++j) {
            const int i = j * 64 + lane;
            const int p = i * 4;             // p = l*64 + s*32 + h
            const int s = (p >> 5) & 1;
            const float v = s ? (1.0f - K) : K;
            ((float4*)(obase + 512))[i] = make_float4(v, v, v, v);
        }
    }
}

// Wave-aggregated compaction of interior rows: 1 atomic per wave (256 total).
__global__ __launch_bounds__(256)
void idx_build(const float* __restrict__ latency, int* __restrict__ count,
               int* __restrict__ idx)
{
    const int s = blockIdx.x * 256 + threadIdx.x;
    const int budget = budget_of(latency[s]);
    const bool interior = (budget > 0 && budget < NGRP);
    const unsigned long long m = __ballot(interior);
    const int lane = threadIdx.x & 63;
    int base = 0;
    if (lane == 0 && m) base = atomicAdd(count, __popcll(m));
    base = __shfl(base, 0);
    if (interior)
        idx[base + __popcll(m & ((1ull << lane) - 1ull))] = s;
}

// One-time W transpose + bf16 hi/lo split into a kb-major TILED layout:
//   wt[colblk 12][ktile 128][kb 4][n 128][e 8]  (u16)
__global__ __launch_bounds__(256)
void convert_w(const float* __restrict__ W, u16* __restrict__ wt_hi,
               u16* __restrict__ wt_lo)
{
    __shared__ float sT[32][33];
    const int n0 = blockIdx.x * 32, k0 = blockIdx.y * 32;
    const int t  = threadIdx.x;
    {
        const int lr = t >> 3, lc = (t & 7) * 4;
        const float4 v = *(const float4*)(W + (size_t)(k0 + lr) * NCOLS + n0 + lc);
        sT[lr][lc] = v.x; sT[lr][lc + 1] = v.y; sT[lr][lc + 2] = v.z; sT[lr][lc + 3] = v.w;
    }
    __syncthreads();
    const int ln = t >> 3, lk = (t & 7) * 4;     // ln: n-local, lk: k-local
    unsigned hb[4], lb[4];
#pragma unroll
    for (int j = 0; j < 4; ++j) {
        const float xv = sT[lk + j][ln];
        const unsigned h = bf16_rne_bits(xv);          // RNE hi for W (one-time)
        const float hf = __uint_as_float(h << 16);
        hb[j] = h;
        lb[j] = bf16_rne_bits(xv - hf);
    }
    uint2 hw, lw;
    hw.x = hb[0] | (hb[1] << 16); hw.y = hb[2] | (hb[3] << 16);
    lw.x = lb[0] | (lb[1] << 16); lw.y = lb[2] | (lb[3] << 16);
    const int gn = n0 + ln;
    const size_t off = ((size_t)((gn >> 7) * 128 + (k0 >> 5)) * 4 + (lk >> 3)) * 1024
                     + (size_t)(gn & 127) * 8 + (lk & 7);
    *(uint2*)(wt_hi + off) = hw;
    *(uint2*)(wt_lo + off) = lw;
}

// bf16x3 MFMA GEMM (128x128 tile, BK=32) + fp32 gumbel-softmax scores.
// r3-proven single-buffer 2-barrier structure (explicit dbuf REGRESSED in r4:
// LDS 74KB + VGPR 100 cut occupancy 26->19%, 618->1034 us — trap #5).
// Grid is (rb=128, cb=12): blocks sharing an x row-panel land on one XCD.
// NOTE: every access to acc[][] must be compile-time-indexed (full unroll).
__global__ __launch_bounds__(256)
void gemm_bf16x3(const float* __restrict__ x, const u16* __restrict__ wt_hi,
                 const u16* __restrict__ wt_lo, const float* __restrict__ bias,
                 const float* __restrict__ uu, const int* __restrict__ idx,
                 const int* __restrict__ count, float* __restrict__ scoresf)
{
    // A planes: [128][40] u16 (pad->80B rows, 2-way banks = free)
    // B planes: [4 kb][128 n][8 e] u16 linear (gload_lds dest; reads 2-way free)
    __shared__ __align__(16) u16 sMem[2 * 5120 + 2 * 4096];   // 36864 B
    __shared__ int rid[128];
    u16* const sAh = sMem;
    u16* const sAl = sMem + 5120;
    u16* const sBh = sMem + 10240;
    u16* const sBl = sMem + 14336;

    const int cnt  = *count;
    const int row0 = blockIdx.x * 128;
    if (row0 >= cnt) return;
    const int cb   = blockIdx.y;
    const int col0 = cb * 128;
    const int t    = threadIdx.x;

    if (t < 128) rid[t] = idx[min(row0 + t, cnt - 1)];
    __syncthreads();

    // ---- A staging maps ----
    const int ar  = t >> 2;             // A rows ar and ar+64
    const int akc = (t & 3) << 3;       // k offset {0,8,16,24}
    const int arow  = ar * 40 + akc;
    const int arow2 = (ar + 64) * 40 + akc;
    const size_t xoff0 = (size_t)rid[ar] * HID + akc;
    const size_t xoff1 = (size_t)rid[ar + 64] * HID + akc;

    // ---- B staging (global_load_lds) ----
    const int wave = t >> 6;
    const size_t bsrc0 = (size_t)cb * 524288 + (size_t)t * 8;  // + kt*4096
    const int ldsB0 = wave * 512;          // issue 0 wave base (u16 units)
    const int ldsB1 = 2048 + wave * 512;   // issue 1

    // ---- fragment maps ----
    const int lane = t & 63;
    const int wr = wave >> 1;           // wave row half
    const int wc = wave & 1;            // wave col half
    const int fr = lane & 15;
    const int kb = lane >> 4;           // 0..3
    const int abase = (wr * 64 + fr) * 40 + kb * 8;
    const int bfrag = kb * 1024 + (wc * 64 + fr) * 8;   // + ni*128

    f32x4 acc[4][4] = {};

    // prefetch A tile 0
    float4 a00 = *(const float4*)(x + xoff0);
    float4 a01 = *(const float4*)(x + xoff0 + 4);
    float4 a10 = *(const float4*)(x + xoff1);
    float4 a11 = *(const float4*)(x + xoff1 + 4);

#pragma unroll 1
    for (int k0 = 0; k0 < HID; k0 += 32) {
        __syncthreads();
        {   // A: convert fp32 -> bf16 hi/lo, combined 16B LDS writes
            uint2 h0, l0, h1, l1;
            split4(a00, h0, l0); split4(a01, h1, l1);
            *(uint4*)&sAh[arow]  = make_uint4(h0.x, h0.y, h1.x, h1.y);
            *(uint4*)&sAl[arow]  = make_uint4(l0.x, l0.y, l1.x, l1.y);
            split4(a10, h0, l0); split4(a11, h1, l1);
            *(uint4*)&sAh[arow2] = make_uint4(h0.x, h0.y, h1.x, h1.y);
            *(uint4*)&sAl[arow2] = make_uint4(l0.x, l0.y, l1.x, l1.y);
        }
        {   // B: async direct-to-LDS, current K-tile (linear, coalesced)
            const size_t bs = bsrc0 + (size_t)(k0 >> 5) * 4096;
            gload16(wt_hi + bs,        sBh + ldsB0);
            gload16(wt_hi + bs + 2048, sBh + ldsB1);
            gload16(wt_lo + bs,        sBl + ldsB0);
            gload16(wt_lo + bs + 2048, sBl + ldsB1);
        }
        __syncthreads();   // drains vmcnt (gload_lds) + lgkm (A writes)

        if (k0 + 32 < HID) {
            a00 = *(const float4*)(x + xoff0 + k0 + 32);
            a01 = *(const float4*)(x + xoff0 + k0 + 36);
            a10 = *(const float4*)(x + xoff1 + k0 + 32);
            a11 = *(const float4*)(x + xoff1 + k0 + 36);
        }

        bf16x8 bh[4], bl[4];
#pragma unroll
        for (int ni = 0; ni < 4; ++ni) {
            bh[ni] = *(const bf16x8*)&sBh[bfrag + ni * 128];
            bl[ni] = *(const bf16x8*)&sBl[bfrag + ni * 128];
        }
#pragma unroll
        for (int mi = 0; mi < 4; ++mi) {
            const bf16x8 ah = *(const bf16x8*)&sAh[abase + mi * 640];
            const bf16x8 al = *(const bf16x8*)&sAl[abase + mi * 640];
#pragma unroll
            for (int ni = 0; ni < 4; ++ni) {
                acc[mi][ni] = __builtin_amdgcn_mfma_f32_16x16x32_bf16(ah, bh[ni], acc[mi][ni], 0, 0, 0);
                acc[mi][ni] = __builtin_amdgcn_mfma_f32_16x16x32_bf16(ah, bl[ni], acc[mi][ni], 0, 0, 0);
                acc[mi][ni] = __builtin_amdgcn_mfma_f32_16x16x32_bf16(al, bh[ni], acc[mi][ni], 0, 0, 0);
            }
        }
    }

    // ---- epilogue: LDS transpose of MFMA layout, then scores ----
    // MFMA D layout: col = lane&15, row = 4*(lane>>4)+r  (per frag)
    float* const sOut = (float*)sMem;                  // 4 waves x [16][68] f32
    float* const sW   = sOut + wave * (16 * 68);
    const int gb = (col0 >> 2) + wc * 16;              // global group base (wave)

#pragma unroll
    for (int mi = 0; mi < 4; ++mi) {
        __syncthreads();
#pragma unroll
        for (int ni = 0; ni < 4; ++ni)
#pragma unroll
            for (int r = 0; r < 4; ++r)
                sW[(kb * 4 + r) * 68 + ni * 16 + fr] = acc[mi][ni][r];
        __syncthreads();

        const int lr    = fr;                          // row 0..15
        const int gq    = kb;                          // group quad 0..3
        const int row_l = wr * 64 + mi * 16 + lr;      // local compact row
        const int cr    = row0 + row_l;
        const int orig  = rid[row_l];
        const float* so = sW + lr * 68 + gq * 16;
        const int g0    = gb + gq * 4;

        float s[4];
#pragma unroll
        for (int j = 0; j < 4; ++j) {
            const int g = g0 + j;
            const float4 lv = *(const float4*)(so + 4 * j);
            const float4 bv = *(const float4*)(bias + 4 * g);
            const float4 uv = *(const float4*)(uu + (size_t)orig * NCOLS + 4 * g);
            s[j] = score_f(lv.x + bv.x, lv.y + bv.y, lv.z + bv.z, lv.w + bv.w, uv);
        }
        *(float4*)&scoresf[(size_t)cr * NGRP + g0] = make_float4(s[0], s[1], s[2], s[3]);
    }
}

// fp32 selection via 4-pass 8-bit RADIX SELECT on u32 score bits (positive
// floats: bit order == value order). Replaces the O(N^2) rank loop (r7
// post-mortem: 96 b128 LDS broadcasts x 6 waves = ~6900 LDS-pipe cyc/block,
// ~150-180us total). Finds T = budget-th largest; kept = bits >= T.
// Wave-aggregated histogram (8 ballots -> equal-byte groups -> 1 LDS atomic
// per group) avoids same-bin atomic serialization from clustered exponents.
// Exact-tie straddle (r < ceq) -> fp64 fallback, semantics identical to r7.
__global__ __launch_bounds__(384)
void select_fast(const float* __restrict__ scoresf, const float* __restrict__ latency,
                 const int* __restrict__ idx, const int* __restrict__ count,
                 float* __restrict__ out, int* __restrict__ ridx,
                 int* __restrict__ rcount, int* __restrict__ rcount2)
{
    const int b = blockIdx.x;
    if (b >= *count) return;
    const int t = threadIdx.x;
    const int orig = idx[b];

    __shared__ int   hist[4][256];
    __shared__ int   wtot[4];
    __shared__ int   sel[3];            // B, S_excl(B), hist[B]
    __shared__ float wred1[6];
    __shared__ int   flag;

    const float sg = scoresf[(size_t)b * NGRP + t];
    const unsigned bg = __float_as_uint(sg);
    const int budget = budget_of(latency[orig]);   // 1..383 here
    const int lane = t & 63;

    for (int i = t; i < 1024; i += 384) (&hist[0][0])[i] = 0;
    if (t == 0) flag = 0;
    __syncthreads();

    unsigned prefix = 0;
    int r = budget, ceq = 0;

#pragma unroll
    for (int p = 3; p >= 0; --p) {
        const int shift = 8 * p;
        const bool match = (p == 3) ? true : (((bg ^ prefix) >> (shift + 8)) == 0);
        const unsigned byte = (bg >> shift) & 255u;
        // wave-aggregate equal (matched, byte) groups
        unsigned long long same = __ballot(match);
#pragma unroll
        for (int bit = 0; bit < 8; ++bit) {
            const unsigned long long bb = __ballot((byte >> bit) & 1u);
            same &= ((byte >> bit) & 1u) ? bb : ~bb;
        }
        if (match && (same & ((1ull << lane) - 1ull)) == 0)   // group leader
            atomicAdd(&hist[p][byte], (int)__popcll(same));
        __syncthreads();

        int v = 0, incl = 0;
        if (t < 256) {
            v = hist[p][t];
            incl = v;
#pragma unroll
            for (int off = 1; off < 64; off <<= 1) {
                const int pv = __shfl(incl, (lane + off) & 63);
                incl += (lane + off < 64) ? pv : 0;
            }
            if (lane == 0) wtot[t >> 6] = incl;   // wave suffix total
        }
        __syncthreads();
        if (t < 256) {
            const int w = t >> 6;
            int add = 0;
            if (w < 1) add += wtot[1];
            if (w < 2) add += wtot[2];
            if (w < 3) add += wtot[3];
            const int S_incl = incl + add;        // count of matched bytes >= t
            const int S_excl = S_incl - v;        // count of matched bytes >  t
            if (S_excl < r && r <= S_incl) { sel[0] = t; sel[1] = S_excl; sel[2] = v; }
        }
        __syncthreads();
        prefix |= ((unsigned)sel[0]) << shift;
        r   -= sel[1];
        ceq  = sel[2];
    }

    if (r < ceq) {     // exact-tie class straddles the cut: fp64 fallback
        if (t == 0) { int s2 = atomicAdd(rcount2, 1); ridx[16383 - s2] = orig | (b << 14); }
        return;
    }
    const bool kept = (bg >= prefix);             // budget keys >= T exactly

    // bnd1 = max over dropped (nonempty: budget <= 383); bnd0 = T itself
    float dv = kept ? -3.0e38f : sg;
#pragma unroll
    for (int off = 32; off; off >>= 1) dv = fmaxf(dv, __shfl_xor(dv, off));
    if (lane == 0) wred1[t >> 6] = dv;
    __syncthreads();
    if (t == 0) {
        float b1 = wred1[0];
#pragma unroll
        for (int w = 1; w < 6; ++w) b1 = fmaxf(b1, wred1[w]);
        if (__uint_as_float(prefix) - b1 < GAP_MIN) {
            flag = 1; ridx[atomicAdd(rcount, 1)] = orig | (b << 14);
        }
    }
    __syncthreads();
    if (flag) return;

    const float keep = kept ? 1.0f : 0.0f;
    float* p = out + (size_t)orig * 2048 + 512 + (size_t)(t >> 4) * 64;
    const int h2 = (t & 15) << 1;
    *(float2*)(p + h2)      = make_float2(keep, keep);
    *(float2*)(p + 32 + h2) = make_float2(1.0f - keep, 1.0f - keep);
}

// Window repair: for each flagged row, only groups whose fp32 score lies in
// [bnd1-MARG, bnd0+MARG] are uncertain (|fp32-fp64| <= ~3e-6 << MARG).
// fp64 scores ONLY for the window (usually 2 groups), ranked within it.
// Pathological rows (window > WMAX, or exact-tie straddle) -> fp64 fallback.
__global__ __launch_bounds__(384)
void window_repair(const float* __restrict__ x, const float* __restrict__ W,
                   const float* __restrict__ bias, const float* __restrict__ u,
                   const float* __restrict__ latency, const float* __restrict__ scoresf,
                   int* __restrict__ ridx, const int* __restrict__ rcount,
                   int* __restrict__ rcount2, float* __restrict__ out)
{
    __shared__ __align__(16) unsigned smu[NGRP];
    __shared__ float  wred0[6], wred1[6];
    __shared__ float  sbnd[2];
    __shared__ double red[6][4];
    __shared__ double s64[WMAX];
    __shared__ int    wg[WMAX];
    __shared__ int    wcnt;

    const int nrep = *rcount;
    const int t = threadIdx.x;

    for (int ib = blockIdx.x; ib < nrep; ib += gridDim.x) {
        const int pk   = ridx[ib];
        const int orig = pk & 0x3FFF;
        const int row  = pk >> 14;

        const float sg = scoresf[(size_t)row * NGRP + t];
        const unsigned bg = __float_as_uint(sg);
        smu[t] = bg;
        if (t == 0) wcnt = 0;
        const int budget = budget_of(latency[orig]);
        __syncthreads();

        int rank = 0;
#pragma unroll 4
        for (int j = 0; j < NGRP; j += 4) {
            const uint4 v = *(const uint4*)&smu[j];
            rank += (v.x > bg) ? 1 : 0;
            rank += (v.y > bg) ? 1 : 0;
            rank += (v.z > bg) ? 1 : 0;
            rank += (v.w > bg) ? 1 : 0;
        }
        const bool kept = (rank < budget);
        const int  ck   = __syncthreads_count(kept ? 1 : 0);

        if (ck != budget) {            // straddle: fp64 fallback
            if (t == 0) { int s2 = atomicAdd(rcount2, 1); ridx[16383 - s2] = pk; }
            __syncthreads();
            continue;
        }
        float kv = kept ? sg : 3.0e38f;
        float dv = kept ? -3.0e38f : sg;
#pragma unroll
        for (int off = 32; off; off >>= 1) {
            kv = fminf(kv, __shfl_xor(kv, off));
            dv = fmaxf(dv, __shfl_xor(dv, off));
        }
        if ((t & 63) == 0) { wred0[t >> 6] = kv; wred1[t >> 6] = dv; }
        __syncthreads();
        if (t == 0) {
            float v0 = wred0[0], v1 = wred1[0];
#pragma unroll
            for (int w = 1; w < 6; ++w) { v0 = fminf(v0, wred0[w]); v1 = fmaxf(v1, wred1[w]); }
            sbnd[0] = v0; sbnd[1] = v1;
        }
        __syncthreads();

        const float b0 = sbnd[0], b1 = sbnd[1];
        const bool hi  = sg > b0 + MARG;
        const bool lo  = sg < b1 - MARG;
        int e_t = -1;
        if (!hi && !lo) {
            e_t = atomicAdd(&wcnt, 1);
            if (e_t < WMAX) wg[e_t] = t;
        }
        const int c_hi   = __syncthreads_count(hi ? 1 : 0);
        const int wcount = wcnt;

        if (wcount > WMAX) {           // pathological: full-fp64 fallback
            if (t == 0) { int s2 = atomicAdd(rcount2, 1); ridx[16383 - s2] = pk; }
            __syncthreads();
            continue;
        }
        const int kwin = budget - c_hi;    // window slots to keep (>=1)

        // fp64 scores for window entries (block-cooperative dot products)
        const float* xr = x + (size_t)orig * HID;
        for (int e = 0; e < wcount; ++e) {
            const int g = wg[e];
            double p0 = 0, p1 = 0, p2 = 0, p3 = 0;
            const float* wcp = W + 4 * g;
            for (int k = t; k < HID; k += 384) {
                const double xv = (double)xr[k];
                const float4 wv = *(const float4*)(wcp + (size_t)k * NCOLS);
                p0 = fma(xv, (double)wv.x, p0);
                p1 = fma(xv, (double)wv.y, p1);
                p2 = fma(xv, (double)wv.z, p2);
                p3 = fma(xv, (double)wv.w, p3);
            }
#pragma unroll
            for (int off = 32; off; off >>= 1) {
                p0 += __shfl_down(p0, off);
                p1 += __shfl_down(p1, off);
                p2 += __shfl_down(p2, off);
                p3 += __shfl_down(p3, off);
            }
            const int wid = t >> 6;
            if ((t & 63) == 0) {
                red[wid][0] = p0; red[wid][1] = p1;
                red[wid][2] = p2; red[wid][3] = p3;
            }
            __syncthreads();
            if (t == 0) {
                double l0 = (double)bias[4 * g + 0], l1 = (double)bias[4 * g + 1];
                double l2 = (double)bias[4 * g + 2], l3 = (double)bias[4 * g + 3];
                for (int w = 0; w < 6; ++w) {
                    l0 += red[w][0]; l1 += red[w][1];
                    l2 += red[w][2]; l3 += red[w][3];
                }
                const float4 uv = *(const float4*)(u + (size_t)orig * NCOLS + 4 * g);
                const double d0 = ((l0 + gumbel_d(uv.x)) - (l1 + gumbel_d(uv.y))) / 5.0;
                const double d1 = ((l2 + gumbel_d(uv.z)) - (l3 + gumbel_d(uv.w))) / 5.0;
                const double q0 = 1.0 / (1.0 + exp(-d0));
                const double q1 = 1.0 / (1.0 + exp(-d1));
                s64[e] = 0.5 * (q0 + q1);
            }
            __syncthreads();
        }

        float keep;
        if (hi)      keep = 1.0f;
        else if (lo) keep = 0.0f;
        else {
            const double se = s64[e_t];
            int r = 0;
            for (int f = 0; f < wcount; ++f)
                r += (s64[f] > se || (s64[f] == se && wg[f] < t)) ? 1 : 0;
            keep = (r < kwin) ? 1.0f : 0.0f;
        }
        float* pp = out + (size_t)orig * 2048 + 512 + (size_t)(t >> 4) * 64;
        const int h2 = (t & 15) << 1;
        *(float2*)(pp + h2)      = make_float2(keep, keep);
        *(float2*)(pp + 32 + h2) = make_float2(1.0f - keep, 1.0f - keep);
        __syncthreads();   // protect smu reuse next iteration
    }
}

// fp64 FALLBACK repair GEMM over pathological rows only (list packed from
// top of ridx). Normally zero active rows; grid-stride keeps grid small.
__global__ __launch_bounds__(256)
void gemm64_repair(const float* __restrict__ x, const float* __restrict__ W,
                   const float* __restrict__ bias, const float* __restrict__ u,
                   const int* __restrict__ ridx, const int* __restrict__ rcount2,
                   double* __restrict__ scores)
{
    __shared__ float As[16][36];
    __shared__ float Bs[16][68];
    __shared__ int   rid[32];

    const int cnt  = *rcount2;
    const int col0 = blockIdx.x * 64;
    const int t    = threadIdx.x;

    for (int row0 = blockIdx.y * 32; row0 < cnt; row0 += gridDim.y * 32) {
        if (t < 32) rid[t] = ridx[16383 - min(row0 + t, cnt - 1)] & 0x3FFF;
        __syncthreads();

        const bool doA = (t < 128);
        const int ar  = t >> 2;            // 0..31 when doA
        const int akc = (t & 3) << 2;
        const int bkr = t >> 4;
        const int bnc = (t & 15) << 2;

        size_t xoff = 0;
        if (doA) xoff = (size_t)rid[ar] * HID + akc;
        const float* wp = W + (size_t)bkr * NCOLS + col0 + bnc;

        const int ty = t >> 4;             // rows 2ty, 2ty+1
        const int tx = t & 15;

        double acc[2][4] = {};

        float4 a0 = make_float4(0, 0, 0, 0);
        if (doA) a0 = *(const float4*)(x + xoff);
        float4 b0 = *(const float4*)(wp);

        for (int k0 = 0; k0 < HID; k0 += 16) {
            __syncthreads();
            if (doA) {
                As[akc + 0][ar] = a0.x; As[akc + 1][ar] = a0.y;
                As[akc + 2][ar] = a0.z; As[akc + 3][ar] = a0.w;
            }
            *(float4*)&Bs[bkr][bnc] = b0;
            __syncthreads();
            if (k0 + 16 < HID) {
                if (doA) a0 = *(const float4*)(x + xoff + k0 + 16);
                b0 = *(const float4*)(wp + (size_t)(k0 + 16) * NCOLS);
            }
#pragma unroll
            for (int k = 0; k < 16; ++k) {
                const double a0d = (double)As[k][ty * 2];
                const double a1d = (double)As[k][ty * 2 + 1];
                const float4 bf  = *(const float4*)&Bs[k][tx * 4];
                const double bd[4] = {(double)bf.x, (double)bf.y, (double)bf.z, (double)bf.w};
#pragma unroll
                for (int j = 0; j < 4; ++j) {
                    acc[0][j] = fma(a0d, bd[j], acc[0][j]);
                    acc[1][j] = fma(a1d, bd[j], acc[1][j]);
                }
            }
        }

        const int g = (col0 >> 2) + tx;
        const double bs0 = (double)bias[4 * g + 0];
        const double bs1 = (double)bias[4 * g + 1];
        const double bs2 = (double)bias[4 * g + 2];
        const double bs3 = (double)bias[4 * g + 3];
#pragma unroll
        for (int i = 0; i < 2; ++i) {
            const int rl   = ty * 2 + i;
            const int cr   = row0 + rl;
            const int orig = rid[rl];
            const float4 uv = *(const float4*)(u + (size_t)orig * NCOLS + 4 * g);
            const double l0 = acc[i][0] + bs0;
            const double l1 = acc[i][1] + bs1;
            const double l2 = acc[i][2] + bs2;
            const double l3 = acc[i][3] + bs3;
            const double d0 = ((l0 + gumbel_d(uv.x)) - (l1 + gumbel_d(uv.y))) / 5.0;
            const double d1 = ((l2 + gumbel_d(uv.z)) - (l3 + gumbel_d(uv.w))) / 5.0;
            const double p0 = 1.0 / (1.0 + exp(-d0));
            const double p1 = 1.0 / (1.0 + exp(-d1));
            scores[(size_t)cr * NGRP + g] = 0.5 * (p0 + p1);
        }
        __syncthreads();   // protect rid/As/Bs before next stride iteration
    }
}

// fp64 selection for fallback rows (exact, with index tie-break). Grid-stride.
__global__ __launch_bounds__(384)
void select_repair(const double* __restrict__ scores, const float* __restrict__ latency,
                   const int* __restrict__ ridx, const int* __restrict__ rcount2,
                   float* __restrict__ out)
{
    const int cnt = *rcount2;
    const int t = threadIdx.x;
    __shared__ __align__(16) double sm[NGRP];

    for (int b = blockIdx.x; b < cnt; b += gridDim.x) {
        const int orig = ridx[16383 - b] & 0x3FFF;

        const double sg = scores[(size_t)b * NGRP + t];
        sm[t] = sg;
        const int budget = budget_of(latency[orig]);
        __syncthreads();

        int rank = 0;
#pragma unroll 4
        for (int j = 0; j < NGRP; j += 2) {
            const double2 v = *(const double2*)&sm[j];
            rank += (v.x > sg || (v.x == sg && (j + 0) < t)) ? 1 : 0;
            rank += (v.y > sg || (v.y == sg && (j + 1) < t)) ? 1 : 0;
        }
        const float keep = (rank < budget) ? 1.0f : 0.0f;

        float* p = out + (size_t)orig * 2048 + 512 + (size_t)(t >> 4) * 64;
        const int h2 = (t & 15) << 1;
        *(float2*)(p + h2)      = make_float2(keep, keep);
        *(float2*)(p + 32 + h2) = make_float2(1.0f - keep, 1.0f - keep);
        __syncthreads();   // protect sm before next stride iteration
    }
}

extern "C" void kernel_launch(void* const* d_in, const int* in_sizes, int n_in,
                              void* d_out, int out_size, void* d_ws, size_t ws_size,
                              hipStream_t stream) {
    const float* x       = (const float*)d_in[0];
    const float* latency = (const float*)d_in[1];
    const float* W       = (const float*)d_in[2];
    const float* bias    = (const float*)d_in[3];
    const float* u       = (const float*)d_in[4];
    float* out           = (float*)d_out;

    // ws layout (total 50,462,976 B):
    //   [count@0, rcount@4, rcount2@8 .. 256B][idx 64KB][ridx 64KB: window
    //   list grows from 0, fallback list grows from index 16383 down]
    //   [WT_hi 12.58MB][WT_lo 12.58MB][scoresf 25.17MB]
    //   scores64 (fallback fp64) ALIASES [WT_hi..]: wt planes dead after
    //   gemm_bf16x3; fallback rows are few, writes stay inside dead region.
    int*    count   = (int*)d_ws;
    int*    rcount  = (int*)((char*)d_ws + 4);
    int*    rcount2 = (int*)((char*)d_ws + 8);
    int*    idx     = (int*)((char*)d_ws + 256);
    int*    ridx    = (int*)((char*)d_ws + 256 + 65536);
    u16*    wt_hi   = (u16*)((char*)d_ws + 131328);
    u16*    wt_lo   = (u16*)((char*)d_ws + 131328 + 12582912);
    float*  scoresf = (float*)((char*)d_ws + 131328 + 25165824);
    double* scores64= (double*)((char*)d_ws + 131328);

    hipMemsetAsync(d_ws, 0, 256, stream);
    convert_w<<<dim3(NCOLS / 32, HID / 32), 256, 0, stream>>>(W, wt_hi, wt_lo);
    prefilter_kernel<<<BATCH / 4, 256, 0, stream>>>(latency, out);
    idx_build<<<BATCH / 256, 256, 0, stream>>>(latency, count, idx);
    gemm_bf16x3<<<dim3(BATCH / 128, NCOLS / 128), 256, 0, stream>>>(
        x, wt_hi, wt_lo, bias, u, idx, count, scoresf);
    select_fast<<<BATCH, NGRP, 0, stream>>>(scoresf, latency, idx, count, out,
                                            ridx, rcount, rcount2);
    window_repair<<<1024, NGRP, 0, stream>>>(x, W, bias, u, latency, scoresf,
                                             ridx, rcount, rcount2, out);
    gemm64_repair<<<dim3(NCOLS / 64, 16), 256, 0, stream>>>(
        x, W, bias, u, ridx, rcount2, scores64);
    select_repair<<<512, NGRP, 0, stream>>>(scores64, latency, ridx, rcount2, out);
}